// Round 16
// baseline (256.878 us; speedup 1.0000x reference)
//
#include <hip/hip_runtime.h>
#include <math.h>

#define B_ 1024
#define S_ 128
#define H_ 1024
#define E_ 16
#define HID_ 1024
#define K_ 4
#define C_ 3
#define EPS_ 1e-5f

// phase-1 mega-kernel block ranges (512 threads / 8 waves per block)
#define NB_CLSG 128
#define OFF_MEAN (NB_CLSG)
#define NB_MEAN 512
#define OFF_WC (OFF_MEAN + NB_MEAN)
#define NB_WC 2048
#define OFF_RT (OFF_WC + NB_WC)
#define NB_RT 128
#define OFF_BC (OFF_RT + NB_RT)
#define NB_BC 2
#define NB_P1 (OFF_BC + NB_BC)

typedef __attribute__((ext_vector_type(8))) __bf16 bf16x8;
typedef __attribute__((ext_vector_type(4))) float f32x4;
typedef __attribute__((ext_vector_type(4))) float fvec4;
typedef __attribute__((ext_vector_type(4))) unsigned short usvec4;
typedef __attribute__((ext_vector_type(8))) unsigned short usvec8;

__device__ __forceinline__ ushort bf16_rn(float f) {
  unsigned u = __float_as_uint(f);
  u += 0x7FFF + ((u >> 16) & 1);
  return (ushort)(u >> 16);
}
__device__ __forceinline__ float bf16_to_f(ushort h) {
  return __uint_as_float(((unsigned)h) << 16);
}
__device__ __forceinline__ void split2(float f, ushort& h, ushort& l) {
  h = bf16_rn(f);
  l = bf16_rn(f - bf16_to_f(h));
}
__device__ __forceinline__ void gload_lds16(const void* g, void* l) {
  __builtin_amdgcn_global_load_lds((const __attribute__((address_space(1))) void*)g,
                                   (__attribute__((address_space(3))) void*)l, 16, 0, 0);
}
// Explicit LDS-DMA drain (rule #18: asm waitcnt + sched_barrier(0)).
#define DMA_DRAIN() do {                                  \
    asm volatile("s_waitcnt vmcnt(0)" ::: "memory");      \
    __builtin_amdgcn_sched_barrier(0);                    \
  } while (0)

__device__ __forceinline__ fvec4 nt_load4f(const float* p) {
  return __builtin_nontemporal_load((const fvec4*)p);
}
__device__ __forceinline__ void st4us(ushort* p, ushort a, ushort b, ushort c, ushort d) {
  usvec4 v; v.x = a; v.y = b; v.z = c; v.w = d;
  *(usvec4*)p = v;
}
__device__ __forceinline__ void nt_store1f(float* p, float v) {
  __builtin_nontemporal_store(v, p);
}
__device__ __forceinline__ void waveRed3(float& s0, float& s1, float& s2) {
#pragma unroll
  for (int off = 32; off; off >>= 1) {
    s0 += __shfl_down(s0, off); s1 += __shfl_down(s1, off); s2 += __shfl_down(s2, off);
  }
}

// ---------------------------------------------------------------------------
// Phase 1 mega-kernel (unchanged): cls@Wd GEMM + mean splits + Wcomb +
// router + bcomb.
// ---------------------------------------------------------------------------
__global__ __launch_bounds__(512) void phase1_kernel(
    const float* __restrict__ hs,
    const float* __restrict__ Wd,
    const float* __restrict__ We2, const float* __restrict__ Wp, const float* __restrict__ bp,
    const float* __restrict__ Wr, const float* __restrict__ br,
    const float* __restrict__ be2,
    ushort* __restrict__ m_hi, ushort* __restrict__ m_lo,
    float* __restrict__ Wcomb, float* __restrict__ bcomb,
    int* __restrict__ topk_idx, float* __restrict__ topk_prob,
    int* __restrict__ counts, int* __restrict__ pairlist,
    float* __restrict__ tA, float* __restrict__ tB) {
  __shared__ __align__(16) ushort ldsAh0[4096], ldsAl0[4096], ldsBh0[4096], ldsBl0[4096];
  __shared__ __align__(16) ushort ldsAh1[4096], ldsAl1[4096], ldsBh1[4096], ldsBl1[4096];
  const int blk = blockIdx.x;
  const int tid = threadIdx.x;
  const int w = tid >> 6, lane = tid & 63;

  if (blk < NB_CLSG) {
    const int n0 = (blk & 7) * 128;
    const int yy = blk >> 3;
    const int mt = yy >> 1, kh = yy & 1;
    const int m0 = mt * 128;
    const int kbase = kh * 512;
    const float* sbase[2];
    size_t kstride;
    int subs0;
    if (w < 4) {
      kstride = 1;
      subs0 = w * 2;
#pragma unroll
      for (int sl = 0; sl < 2; ++sl) {
        int s = subs0 + sl;
        int b = m0 + s * 16 + (lane & 15);
        sbase[sl] = hs + (size_t)b * (S_ * H_) + ((lane >> 4) << 3);
      }
    } else {
      kstride = H_;
      subs0 = (w - 4) * 2;
#pragma unroll
      for (int sl = 0; sl < 2; ++sl) {
        int s = subs0 + sl;
        int col = n0 + s * 16 + (lane & 15);
        sbase[sl] = Wd + col + (size_t)((lane >> 4) << 3) * H_;
      }
    }
    const int wr = w >> 2, wc = w & 3;
    f32x4 acc[4][2] = {};

    auto stage = [&](int kofs, ushort* dAh, ushort* dAl, ushort* dBh, ushort* dBl) {
      ushort* dh = (w < 4) ? dAh : dBh;
      ushort* dl = (w < 4) ? dAl : dBl;
#pragma unroll
      for (int sl = 0; sl < 2; ++sl) {
        const float* p = sbase[sl] + (size_t)kofs * kstride;
        float f[8];
        if (w < 4) {
          fvec4 v0 = nt_load4f(p);
          fvec4 v1 = nt_load4f(p + 4);
          f[0] = v0.x; f[1] = v0.y; f[2] = v0.z; f[3] = v0.w;
          f[4] = v1.x; f[5] = v1.y; f[6] = v1.z; f[7] = v1.w;
        } else {
#pragma unroll
          for (int j = 0; j < 8; ++j) f[j] = p[(size_t)j * H_];
        }
        usvec8 vh, vl;
#pragma unroll
        for (int j = 0; j < 8; ++j) {
          ushort hi, lo;
          split2(f[j], hi, lo);
          vh[j] = hi; vl[j] = lo;
        }
        const int off = (subs0 + sl) * 512 + lane * 8;
        *(usvec8*)&dh[off] = vh;
        *(usvec8*)&dl[off] = vl;
      }
    };
    auto compute = [&](const ushort* Ah, const ushort* Al,
                       const ushort* Bh, const ushort* Bl) {
      bf16x8 ah[4], al[4], bh[2], bl[2];
#pragma unroll
      for (int i = 0; i < 4; ++i) {
        int off = (wr * 4 + i) * 512 + lane * 8;
        ah[i] = *(const bf16x8*)&Ah[off];
        al[i] = *(const bf16x8*)&Al[off];
      }
#pragma unroll
      for (int j = 0; j < 2; ++j) {
        int off = (wc * 2 + j) * 512 + lane * 8;
        bh[j] = *(const bf16x8*)&Bh[off];
        bl[j] = *(const bf16x8*)&Bl[off];
      }
#pragma unroll
      for (int i = 0; i < 4; ++i)
#pragma unroll
        for (int j = 0; j < 2; ++j) {
          acc[i][j] = __builtin_amdgcn_mfma_f32_16x16x32_bf16(ah[i], bh[j], acc[i][j], 0, 0, 0);
          acc[i][j] = __builtin_amdgcn_mfma_f32_16x16x32_bf16(ah[i], bl[j], acc[i][j], 0, 0, 0);
          acc[i][j] = __builtin_amdgcn_mfma_f32_16x16x32_bf16(al[i], bh[j], acc[i][j], 0, 0, 0);
        }
    };

    stage(kbase, ldsAh0, ldsAl0, ldsBh0, ldsBl0);
    DMA_DRAIN();
    __syncthreads();
#pragma unroll 1
    for (int tt = 0; tt < 8; ++tt) {
      const int t0 = tt * 2;
      stage(kbase + (t0 + 1) * 32, ldsAh1, ldsAl1, ldsBh1, ldsBl1);
      compute(ldsAh0, ldsAl0, ldsBh0, ldsBl0);
      DMA_DRAIN();
      __syncthreads();
      if (tt < 7) stage(kbase + (t0 + 2) * 32, ldsAh0, ldsAl0, ldsBh0, ldsBl0);
      compute(ldsAh1, ldsAl1, ldsBh1, ldsBl1);
      DMA_DRAIN();
      __syncthreads();
    }
    const int lr = (lane >> 4) << 2, lc = lane & 15;
    float* tp = kh ? tB : tA;
#pragma unroll
    for (int i = 0; i < 4; ++i) {
      int row = m0 + wr * 64 + i * 16 + lr;
#pragma unroll
      for (int j = 0; j < 2; ++j) {
        int col = n0 + wc * 32 + j * 16 + lc;
#pragma unroll
        for (int r = 0; r < 4; ++r)
          nt_store1f(&tp[(size_t)(row + r) * H_ + col], acc[i][j][r]);
      }
    }
  } else if (blk < OFF_WC) {
    int gid = (blk - OFF_MEAN) * 512 + tid;
    int b = gid >> 8;
    int h4 = (gid & 255) << 2;
    const float* p = hs + (size_t)b * S_ * H_ + h4;
    fvec4 v0 = nt_load4f(p);
    float sx = v0.x, sy = v0.y, sz = v0.z, sw = v0.w;
#pragma unroll 8
    for (int s = 1; s < S_; ++s) {
      fvec4 v = nt_load4f(p + (size_t)s * H_);
      sx += v.x; sy += v.y; sz += v.z; sw += v.w;
    }
    const float inv = 1.0f / (float)S_;
    float mv[4] = {sx * inv, sy * inv, sz * inv, sw * inv};
    ushort mh[4], ml[4];
#pragma unroll
    for (int i = 0; i < 4; ++i) split2(mv[i], mh[i], ml[i]);
    size_t o = (size_t)b * H_ + h4;
    st4us(&m_hi[o], mh[0], mh[1], mh[2], mh[3]);
    st4us(&m_lo[o], ml[0], ml[1], ml[2], ml[3]);
  } else if (blk < OFF_RT) {
    const int row = (blk - OFF_WC) * 8 + w;
    const float* wrp = We2 + (size_t)row * HID_;
    float s0 = 0, s1 = 0, s2 = 0;
#pragma unroll
    for (int it = 0; it < 4; ++it) {
      const int f0 = it * 256 + lane * 4;
      fvec4 v = nt_load4f(&wrp[f0]);
      s0 = fmaf(v.x, Wp[(f0 + 0) * 3 + 0], s0);
      s1 = fmaf(v.x, Wp[(f0 + 0) * 3 + 1], s1);
      s2 = fmaf(v.x, Wp[(f0 + 0) * 3 + 2], s2);
      s0 = fmaf(v.y, Wp[(f0 + 1) * 3 + 0], s0);
      s1 = fmaf(v.y, Wp[(f0 + 1) * 3 + 1], s1);
      s2 = fmaf(v.y, Wp[(f0 + 1) * 3 + 2], s2);
      s0 = fmaf(v.z, Wp[(f0 + 2) * 3 + 0], s0);
      s1 = fmaf(v.z, Wp[(f0 + 2) * 3 + 1], s1);
      s2 = fmaf(v.z, Wp[(f0 + 2) * 3 + 2], s2);
      s0 = fmaf(v.w, Wp[(f0 + 3) * 3 + 0], s0);
      s1 = fmaf(v.w, Wp[(f0 + 3) * 3 + 1], s1);
      s2 = fmaf(v.w, Wp[(f0 + 3) * 3 + 2], s2);
    }
    waveRed3(s0, s1, s2);
    if (lane == 0) {
      Wcomb[row * 3 + 0] = s0; Wcomb[row * 3 + 1] = s1; Wcomb[row * 3 + 2] = s2;
    }
  } else if (blk < OFF_BC) {
    const int b = (blk - OFF_RT) * 8 + w;
    const float* cls = hs + (size_t)b * S_ * H_;
    const int e = lane & 15, part = lane >> 4;
    float sum = 0.0f;
    for (int i = part * 256; i < part * 256 + 256; ++i)
      sum = fmaf(cls[i], Wr[i * E_ + e], sum);
    sum += __shfl_down(sum, 32);
    sum += __shfl_down(sum, 16);
    float lg[E_];
#pragma unroll
    for (int i = 0; i < E_; ++i) lg[i] = __shfl(sum, i);
    if (lane == 0) {
      for (int i = 0; i < E_; ++i) lg[i] += br[i];
      int idx[K_]; float tv[K_];
      for (int k = 0; k < K_; ++k) {
        int bi = 0; float bv = -1e30f;
        for (int i = 0; i < E_; ++i) { if (lg[i] > bv) { bv = lg[i]; bi = i; } }
        idx[k] = bi; tv[k] = bv; lg[bi] = -1e30f;
      }
      float mx = tv[0], ssum = 0.0f, p[K_];
      for (int k = 0; k < K_; ++k) { p[k] = expf(tv[k] - mx); ssum += p[k]; }
      for (int k = 0; k < K_; ++k) {
        p[k] /= ssum;
        topk_idx[b * K_ + k] = idx[k];
        topk_prob[b * K_ + k] = p[k];
        int pos = atomicAdd(&counts[idx[k]], 1);
        pairlist[idx[k] * B_ + pos] = b * K_ + k;
      }
    }
  } else {
    const int e = (blk - OFF_BC) * 8 + w;
    const float* wrp = be2 + (size_t)e * HID_;
    float s0 = 0, s1 = 0, s2 = 0;
    for (int f = lane; f < HID_; f += 64) {
      float v = wrp[f];
      s0 = fmaf(v, Wp[f * 3 + 0], s0);
      s1 = fmaf(v, Wp[f * 3 + 1], s1);
      s2 = fmaf(v, Wp[f * 3 + 2], s2);
    }
    waveRed3(s0, s1, s2);
    if (lane == 0) {
      bcomb[e * 3 + 0] = s0 + bp[0]; bcomb[e * 3 + 1] = s1 + bp[1]; bcomb[e * 3 + 2] = s2 + bp[2];
    }
  }
}

// ---------------------------------------------------------------------------
// Phase 2: grouped expert GEMM with SHARED-B. FIX vs R15: blockIdx.y in [0,8)
// encodes (mt-pair, kh): mtp = y>>1 covers rows [mtp*256, mtp*256+256) so the
// full worst-case 1024 rows/expert are reachable (R15 only covered 256 ->
// poison tails for experts with n_e > 256). Blocks with mtp*256 >= n_e exit.
// ---------------------------------------------------------------------------
__global__ __launch_bounds__(512) void expert_gemm(
    const ushort* __restrict__ m_hi, const ushort* __restrict__ m_lo,
    const float* __restrict__ We1,
    const int* __restrict__ counts, const int* __restrict__ pairlist,
    float* __restrict__ h1A, float* __restrict__ h1B) {
  __shared__ __align__(16) ushort A0h0[4096], A0l0[4096], A0h1[4096], A0l1[4096];
  __shared__ __align__(16) ushort A1h0[4096], A1l0[4096], A1h1[4096], A1l1[4096];
  __shared__ __align__(16) ushort B0h[4096], B0l[4096], B1h[4096], B1l[4096];
  const int z = blockIdx.z;
  const int tid = threadIdx.x;
  const int lane = tid & 63, w = tid >> 6;
  const int mtp = blockIdx.y >> 1, kh = blockIdx.y & 1;
  const int m0base = mtp * 256;
  const int n0 = blockIdx.x * 128;
  const int kbase = kh * 512;
  const int n_e = counts[z];
  if (m0base >= n_e) return;

  const ushort* srcp[8];
  ushort* dstA0 = nullptr; ushort* dstA1 = nullptr;
  const float* bbase[2];
  int bsub[2];
  if (w < 4) {
    const int amt = w >> 1;     // m-tile 0 or 1 within the pair
    const int ahl = w & 1;      // 0 = hi, 1 = lo
    dstA0 = (w == 0) ? A0h0 : (w == 1) ? A0l0 : (w == 2) ? A0h1 : A0l1;
    dstA1 = (w == 0) ? A1h0 : (w == 1) ? A1l0 : (w == 2) ? A1h1 : A1l1;
    const ushort* sbase = (ahl == 0) ? m_hi : m_lo;
#pragma unroll
    for (int s = 0; s < 8; ++s) {
      int r = m0base + amt * 128 + s * 16 + (lane & 15);
      if (r >= n_e) r = n_e - 1;
      r = pairlist[z * B_ + r] >> 2;
      srcp[s] = sbase + (size_t)r * H_ + ((lane >> 4) << 3);
    }
  } else {
    const float* Wfp = We1 + (size_t)z * H_ * HID_;
#pragma unroll
    for (int sl = 0; sl < 2; ++sl) {
      int s = (w - 4) * 2 + sl;
      bsub[sl] = s;
      int col = n0 + s * 16 + (lane & 15);
      bbase[sl] = Wfp + col + (size_t)((lane >> 4) << 3) * HID_;
    }
  }

  const int wr = w >> 2, wc = w & 3;
  f32x4 acc0[4][2] = {};
  f32x4 acc1[4][2] = {};

  auto stageA = [&](int kofs, ushort* dst) {
#pragma unroll
    for (int s = 0; s < 8; ++s)
      gload_lds16(srcp[s] + kofs, dst + s * 512);
  };
  auto stageB = [&](int kofs, ushort* dBh, ushort* dBl) {
#pragma unroll
    for (int sl = 0; sl < 2; ++sl) {
      const float* bp = bbase[sl] + (size_t)kofs * HID_;
      float f[8];
#pragma unroll
      for (int j = 0; j < 8; ++j) f[j] = bp[(size_t)j * HID_];
      usvec8 vh, vl;
#pragma unroll
      for (int j = 0; j < 8; ++j) {
        ushort hi, lo;
        split2(f[j], hi, lo);
        vh[j] = hi; vl[j] = lo;
      }
      const int off = bsub[sl] * 512 + lane * 8;
      *(usvec8*)&dBh[off] = vh;
      *(usvec8*)&dBl[off] = vl;
    }
  };
  auto stage_buf0 = [&](int kofs) {
    if (w < 4) stageA(kofs, dstA0);
    else stageB(kofs, B0h, B0l);
  };
  auto stage_buf1 = [&](int kofs) {
    if (w < 4) stageA(kofs, dstA1);
    else stageB(kofs, B1h, B1l);
  };
  auto compute = [&](const ushort* Ah0, const ushort* Al0,
                     const ushort* Ah1, const ushort* Al1,
                     const ushort* Bh, const ushort* Bl) {
    bf16x8 bh[2], bl[2];
#pragma unroll
    for (int j = 0; j < 2; ++j) {
      int off = (wc * 2 + j) * 512 + lane * 8;
      bh[j] = *(const bf16x8*)&Bh[off];
      bl[j] = *(const bf16x8*)&Bl[off];
    }
    {
      bf16x8 ah[4], al[4];
#pragma unroll
      for (int i = 0; i < 4; ++i) {
        int off = (wr * 4 + i) * 512 + lane * 8;
        ah[i] = *(const bf16x8*)&Ah0[off];
        al[i] = *(const bf16x8*)&Al0[off];
      }
#pragma unroll
      for (int i = 0; i < 4; ++i)
#pragma unroll
        for (int j = 0; j < 2; ++j) {
          acc0[i][j] = __builtin_amdgcn_mfma_f32_16x16x32_bf16(ah[i], bh[j], acc0[i][j], 0, 0, 0);
          acc0[i][j] = __builtin_amdgcn_mfma_f32_16x16x32_bf16(ah[i], bl[j], acc0[i][j], 0, 0, 0);
          acc0[i][j] = __builtin_amdgcn_mfma_f32_16x16x32_bf16(al[i], bh[j], acc0[i][j], 0, 0, 0);
        }
    }
    {
      bf16x8 ah[4], al[4];
#pragma unroll
      for (int i = 0; i < 4; ++i) {
        int off = (wr * 4 + i) * 512 + lane * 8;
        ah[i] = *(const bf16x8*)&Ah1[off];
        al[i] = *(const bf16x8*)&Al1[off];
      }
#pragma unroll
      for (int i = 0; i < 4; ++i)
#pragma unroll
        for (int j = 0; j < 2; ++j) {
          acc1[i][j] = __builtin_amdgcn_mfma_f32_16x16x32_bf16(ah[i], bh[j], acc1[i][j], 0, 0, 0);
          acc1[i][j] = __builtin_amdgcn_mfma_f32_16x16x32_bf16(ah[i], bl[j], acc1[i][j], 0, 0, 0);
          acc1[i][j] = __builtin_amdgcn_mfma_f32_16x16x32_bf16(al[i], bh[j], acc1[i][j], 0, 0, 0);
        }
    }
  };

  stage_buf0(kbase);
  DMA_DRAIN();
  __syncthreads();
#pragma unroll 1
  for (int tt = 0; tt < 8; ++tt) {
    const int t0 = tt * 2;
    stage_buf1(kbase + (t0 + 1) * 32);
    compute(A0h0, A0l0, A0h1, A0l1, B0h, B0l);
    DMA_DRAIN();
    __syncthreads();
    if (tt < 7) stage_buf0(kbase + (t0 + 2) * 32);
    compute(A1h0, A1l0, A1h1, A1l1, B1h, B1l);
    DMA_DRAIN();
    __syncthreads();
  }

  const int lr = (lane >> 4) << 2, lc = lane & 15;
  float* hp = kh ? h1B : h1A;
#pragma unroll
  for (int mt = 0; mt < 2; ++mt) {
#pragma unroll
    for (int i = 0; i < 4; ++i) {
      int pr[4]; bool ok[4];
#pragma unroll
      for (int r = 0; r < 4; ++r) {
        int li = m0base + mt * 128 + wr * 64 + i * 16 + lr + r;
        ok[r] = li < n_e;
        pr[r] = pairlist[z * B_ + (ok[r] ? li : n_e - 1)];
      }
#pragma unroll
      for (int j = 0; j < 2; ++j) {
        int col = n0 + wc * 32 + j * 16 + lc;
#pragma unroll
        for (int r = 0; r < 4; ++r) {
          float v = mt ? acc1[i][j][r] : acc0[i][j][r];
          if (ok[r]) nt_store1f(&hp[(size_t)pr[r] * HID_ + col], v);
        }
      }
    }
  }
}

// ---------------------------------------------------------------------------
// Phase 3: fused epilogue (unchanged). One block per sample b.
// ---------------------------------------------------------------------------
__global__ __launch_bounds__(256) void epi_kernel(
    const float* __restrict__ tA, const float* __restrict__ tB,
    const float* __restrict__ bd,
    const float* __restrict__ Wo, const float* __restrict__ bo,
    const float* __restrict__ h1A, const float* __restrict__ h1B,
    const float* __restrict__ be1,
    const float* __restrict__ g1, const float* __restrict__ beta1,
    const int* __restrict__ topk_idx, const float* __restrict__ topk_prob,
    const float* __restrict__ Wcomb, const float* __restrict__ bcomb,
    const float* __restrict__ Wf1, const float* __restrict__ bf1,
    const float* __restrict__ gf, const float* __restrict__ betaf,
    const float* __restrict__ Wf2, const float* __restrict__ bf2,
    float* __restrict__ out) {
  const int b = blockIdx.x;
  const int tid = threadIdx.x;
  const int w = tid >> 6, lane = tid & 63;
  __shared__ float sCtr[4][3];
  __shared__ float sOl[4][3];

  const int pair = b * K_ + w;
  const int e = topk_idx[pair];
  const float prob = topk_prob[pair];
  const float* hrA = h1A + (size_t)pair * HID_;
  const float* hrB = h1B + (size_t)pair * HID_;
  const float* ber = be1 + (size_t)e * HID_;
  float x[4][4];
#pragma unroll
  for (int q = 0; q < 4; ++q) {
    const int d = q * 256 + lane * 4;
    fvec4 a = nt_load4f(&hrA[d]);
    fvec4 bq = nt_load4f(&hrB[d]);
    float4 be = *(const float4*)&ber[d];
    x[q][0] = a.x + bq.x + be.x; x[q][1] = a.y + bq.y + be.y;
    x[q][2] = a.z + bq.z + be.z; x[q][3] = a.w + bq.w + be.w;
  }
  float s = 0;
#pragma unroll
  for (int q = 0; q < 4; ++q) s += x[q][0] + x[q][1] + x[q][2] + x[q][3];
#pragma unroll
  for (int off = 32; off; off >>= 1) s += __shfl_down(s, off);
  const float mu = __shfl(s, 0) * (1.0f / HID_);
  float sq = 0;
#pragma unroll
  for (int q = 0; q < 4; ++q)
#pragma unroll
    for (int i = 0; i < 4; ++i) {
      float d = x[q][i] - mu;
      sq += d * d;
    }
#pragma unroll
  for (int off = 32; off; off >>= 1) sq += __shfl_down(sq, off);
  const float inv = 1.0f / sqrtf(__shfl(sq, 0) * (1.0f / HID_) + EPS_);
  float c0 = 0, c1 = 0, c2 = 0;
#pragma unroll
  for (int q = 0; q < 4; ++q) {
    const int d = q * 256 + lane * 4;
    float4 gg = *(const float4*)&g1[(size_t)e * HID_ + d];
    float4 bb = *(const float4*)&beta1[(size_t)e * HID_ + d];
    float gv[4] = {gg.x, gg.y, gg.z, gg.w};
    float bv[4] = {bb.x, bb.y, bb.z, bb.w};
#pragma unroll
    for (int i = 0; i < 4; ++i) {
      float v = (x[q][i] - mu) * inv * gv[i] + bv[i];
      v = 0.5f * v * (1.0f + erff(v * 0.70710678118654752440f));  // exact gelu
      const float* wc = &Wcomb[(size_t)(e * HID_ + d + i) * 3];
      c0 = fmaf(v, wc[0], c0); c1 = fmaf(v, wc[1], c1); c2 = fmaf(v, wc[2], c2);
    }
  }
  waveRed3(c0, c1, c2);
  if (lane == 0) {
    sCtr[w][0] = prob * (c0 + bcomb[e * 3 + 0]);
    sCtr[w][1] = prob * (c1 + bcomb[e * 3 + 1]);
    sCtr[w][2] = prob * (c2 + bcomb[e * 3 + 2]);
  }

  {
    const int h0 = w * 256 + lane * 4;
    fvec4 ta = nt_load4f(&tA[(size_t)b * H_ + h0]);
    fvec4 tb = nt_load4f(&tB[(size_t)b * H_ + h0]);
    float4 bdv = *(const float4*)&bd[h0];
    float tvv[4] = {tanhf(ta.x + tb.x + bdv.x), tanhf(ta.y + tb.y + bdv.y),
                    tanhf(ta.z + tb.z + bdv.z), tanhf(ta.w + tb.w + bdv.w)};
    float o0 = 0, o1 = 0, o2 = 0;
#pragma unroll
    for (int i = 0; i < 4; ++i) {
      const float* wo = &Wo[(size_t)(h0 + i) * 3];
      o0 = fmaf(tvv[i], wo[0], o0); o1 = fmaf(tvv[i], wo[1], o1); o2 = fmaf(tvv[i], wo[2], o2);
    }
    waveRed3(o0, o1, o2);
    if (lane == 0) { sOl[w][0] = o0; sOl[w][1] = o1; sOl[w][2] = o2; }
  }
  __syncthreads();

  if (tid == 0) {
    float comb[6];
#pragma unroll
    for (int c = 0; c < 3; ++c) {
      comb[c] = sOl[0][c] + sOl[1][c] + sOl[2][c] + sOl[3][c] + bo[c];
      comb[3 + c] = sCtr[0][c] + sCtr[1][c] + sCtr[2][c] + sCtr[3][c];
    }
    float z[3];
#pragma unroll
    for (int c = 0; c < 3; ++c) {
      float sv = bf1[c];
#pragma unroll
      for (int i = 0; i < 6; ++i) sv = fmaf(comb[i], Wf1[i * 3 + c], sv);
      z[c] = sv;
    }
    float mu3 = (z[0] + z[1] + z[2]) * (1.0f / 3.0f);
    float v0 = z[0] - mu3, v1 = z[1] - mu3, v2 = z[2] - mu3;
    float var = (v0 * v0 + v1 * v1 + v2 * v2) * (1.0f / 3.0f);
    float inv3 = 1.0f / sqrtf(var + EPS_);
    float r[3];
#pragma unroll
    for (int c = 0; c < 3; ++c) {
      float zz = (z[c] - mu3) * inv3 * gf[c] + betaf[c];
      r[c] = zz > 0.0f ? zz : 0.0f;
    }
#pragma unroll
    for (int c = 0; c < 3; ++c) {
      float sv = bf2[c];
#pragma unroll
      for (int i = 0; i < 3; ++i) sv = fmaf(r[i], Wf2[i * 3 + c], sv);
      out[b * 3 + c] = sv;
    }
  }
}

// ---------------------------------------------------------------------------
extern "C" void kernel_launch(void* const* d_in, const int* in_sizes, int n_in,
                              void* d_out, int out_size, void* d_ws, size_t ws_size,
                              hipStream_t stream) {
  const float* hs    = (const float*)d_in[0];
  const float* Wd    = (const float*)d_in[1];
  const float* bd    = (const float*)d_in[2];
  const float* Wo    = (const float*)d_in[3];
  const float* bo    = (const float*)d_in[4];
  const float* Wr    = (const float*)d_in[5];
  const float* br    = (const float*)d_in[6];
  const float* We1   = (const float*)d_in[7];
  const float* be1   = (const float*)d_in[8];
  const float* g1    = (const float*)d_in[9];
  const float* beta1 = (const float*)d_in[10];
  const float* We2   = (const float*)d_in[11];
  const float* be2   = (const float*)d_in[12];
  const float* Wp    = (const float*)d_in[13];
  const float* bp    = (const float*)d_in[14];
  const float* Wf1   = (const float*)d_in[15];
  const float* bf1   = (const float*)d_in[16];
  const float* gf    = (const float*)d_in[17];
  const float* betaf = (const float*)d_in[18];
  const float* Wf2   = (const float*)d_in[19];
  const float* bf2   = (const float*)d_in[20];
  float* out = (float*)d_out;

  char* w = (char*)d_ws;
  size_t off = 0;
  auto alloc = [&](size_t bytes) {
    void* p = w + off;
    off = (off + bytes + 255) & ~(size_t)255;
    return p;
  };
  ushort* m_hi   = (ushort*)alloc((size_t)B_ * H_ * 2);
  ushort* m_lo   = (ushort*)alloc((size_t)B_ * H_ * 2);
  float* ws_tA   = (float*)alloc((size_t)B_ * H_ * 4);
  float* ws_tB   = (float*)alloc((size_t)B_ * H_ * 4);
  float* ws_h1A  = (float*)alloc((size_t)B_ * K_ * HID_ * 4);
  float* ws_h1B  = (float*)alloc((size_t)B_ * K_ * HID_ * 4);
  float* ws_wc   = (float*)alloc((size_t)E_ * HID_ * 3 * 4);
  float* ws_bc   = (float*)alloc(E_ * 3 * 4);
  float* ws_prob = (float*)alloc(B_ * K_ * 4);
  int* ws_idx = (int*)alloc(B_ * K_ * 4);
  int* ws_cnt = (int*)alloc(E_ * 4);
  int* ws_pl  = (int*)alloc(E_ * B_ * 4);
  if (off > ws_size) return;

  hipMemsetAsync(ws_cnt, 0, E_ * sizeof(int), stream);

  phase1_kernel<<<NB_P1, 512, 0, stream>>>(hs, Wd, We2, Wp, bp, Wr, br, be2,
                                           m_hi, m_lo, ws_wc, ws_bc,
                                           ws_idx, ws_prob, ws_cnt, ws_pl,
                                           ws_tA, ws_tB);
  expert_gemm<<<dim3(8, 8, 16), 512, 0, stream>>>(m_hi, m_lo, We1, ws_cnt, ws_pl,
                                                  ws_h1A, ws_h1B);
  epi_kernel<<<B_, 256, 0, stream>>>(ws_tA, ws_tB, bd, Wo, bo, ws_h1A, ws_h1B, be1,
                                     g1, beta1, ws_idx, ws_prob, ws_wc, ws_bc,
                                     Wf1, bf1, gf, betaf, Wf2, bf2, out);
}

// Round 17
// 252.941 us; speedup vs baseline: 1.0156x; 1.0156x over previous
//
#include <hip/hip_runtime.h>
#include <math.h>

#define B_ 1024
#define S_ 128
#define H_ 1024
#define E_ 16
#define HID_ 1024
#define K_ 4
#define C_ 3
#define EPS_ 1e-5f

// prep kernel segment offsets
#define NB_MEAN 1024
#define NB_WC 4096
#define NB_RT 256
#define NB_BC 4
#define OFF_WC (NB_MEAN)
#define OFF_RT (OFF_WC + NB_WC)
#define OFF_BC (OFF_RT + NB_RT)
#define NB_PREP (OFF_BC + NB_BC)

typedef __attribute__((ext_vector_type(8))) __bf16 bf16x8;
typedef __attribute__((ext_vector_type(4))) float f32x4;
typedef __attribute__((ext_vector_type(4))) float fvec4;
typedef __attribute__((ext_vector_type(4))) unsigned short usvec4;
typedef __attribute__((ext_vector_type(8))) unsigned short usvec8;

__device__ __forceinline__ ushort bf16_rn(float f) {
  unsigned u = __float_as_uint(f);
  u += 0x7FFF + ((u >> 16) & 1);
  return (ushort)(u >> 16);
}
__device__ __forceinline__ float bf16_to_f(ushort h) {
  return __uint_as_float(((unsigned)h) << 16);
}
__device__ __forceinline__ void split2(float f, ushort& h, ushort& l) {
  h = bf16_rn(f);
  l = bf16_rn(f - bf16_to_f(h));
}
__device__ __forceinline__ void gload_lds16(const void* g, void* l) {
  __builtin_amdgcn_global_load_lds((const __attribute__((address_space(1))) void*)g,
                                   (__attribute__((address_space(3))) void*)l, 16, 0, 0);
}
// Explicit LDS-DMA drain (rule #18: asm waitcnt + sched_barrier(0)).
#define DMA_DRAIN() do {                                  \
    asm volatile("s_waitcnt vmcnt(0)" ::: "memory");      \
    __builtin_amdgcn_sched_barrier(0);                    \
  } while (0)

__device__ __forceinline__ fvec4 nt_load4f(const float* p) {
  return __builtin_nontemporal_load((const fvec4*)p);
}
__device__ __forceinline__ void st4us(ushort* p, ushort a, ushort b, ushort c, ushort d) {
  usvec4 v; v.x = a; v.y = b; v.z = c; v.w = d;
  *(usvec4*)p = v;
}
__device__ __forceinline__ void nt_store1f(float* p, float v) {
  __builtin_nontemporal_store(v, p);
}
__device__ __forceinline__ void waveRed3(float& s0, float& s1, float& s2) {
#pragma unroll
  for (int off = 32; off; off >>= 1) {
    s0 += __shfl_down(s0, off); s1 += __shfl_down(s1, off); s2 += __shfl_down(s2, off);
  }
}

// ---------------------------------------------------------------------------
// Phase A: prep — mean->m splits (cls splits REMOVED: cls-GEMM now reads hs
// fp32 directly), Wcomb, router, bcomb.
// ---------------------------------------------------------------------------
__global__ __launch_bounds__(256) void prep_kernel(
    const float* __restrict__ hs,
    const float* __restrict__ We2, const float* __restrict__ Wp, const float* __restrict__ bp,
    const float* __restrict__ Wr, const float* __restrict__ br,
    const float* __restrict__ be2,
    ushort* __restrict__ m_hi, ushort* __restrict__ m_lo,
    float* __restrict__ Wcomb, float* __restrict__ bcomb,
    int* __restrict__ topk_idx, float* __restrict__ topk_prob,
    int* __restrict__ counts, int* __restrict__ pairlist) {
  const int blk = blockIdx.x;
  const int tid = threadIdx.x;

  if (blk < NB_MEAN) {
    int gid = blk * 256 + tid;
    int b = gid >> 8;
    int h4 = (gid & 255) << 2;
    const float* p = hs + (size_t)b * S_ * H_ + h4;
    fvec4 v0 = nt_load4f(p);
    float sx = v0.x, sy = v0.y, sz = v0.z, sw = v0.w;
#pragma unroll 8
    for (int s = 1; s < S_; ++s) {
      fvec4 v = nt_load4f(p + (size_t)s * H_);
      sx += v.x; sy += v.y; sz += v.z; sw += v.w;
    }
    const float inv = 1.0f / (float)S_;
    float mv[4] = {sx * inv, sy * inv, sz * inv, sw * inv};
    ushort mh[4], ml[4];
#pragma unroll
    for (int i = 0; i < 4; ++i) split2(mv[i], mh[i], ml[i]);
    size_t o = (size_t)b * H_ + h4;
    st4us(&m_hi[o], mh[0], mh[1], mh[2], mh[3]);
    st4us(&m_lo[o], ml[0], ml[1], ml[2], ml[3]);
  } else if (blk < OFF_RT) {
    // ---- Wcomb[row,:] = We2[row,:] @ Wp — float4 loads ----
    const int row = (blk - OFF_WC) * 4 + (tid >> 6);
    const int lane = tid & 63;
    const float* wrp = We2 + (size_t)row * HID_;
    float s0 = 0, s1 = 0, s2 = 0;
#pragma unroll
    for (int it = 0; it < 4; ++it) {
      const int f0 = it * 256 + lane * 4;
      fvec4 v = nt_load4f(&wrp[f0]);
      s0 = fmaf(v.x, Wp[(f0 + 0) * 3 + 0], s0);
      s1 = fmaf(v.x, Wp[(f0 + 0) * 3 + 1], s1);
      s2 = fmaf(v.x, Wp[(f0 + 0) * 3 + 2], s2);
      s0 = fmaf(v.y, Wp[(f0 + 1) * 3 + 0], s0);
      s1 = fmaf(v.y, Wp[(f0 + 1) * 3 + 1], s1);
      s2 = fmaf(v.y, Wp[(f0 + 1) * 3 + 2], s2);
      s0 = fmaf(v.z, Wp[(f0 + 2) * 3 + 0], s0);
      s1 = fmaf(v.z, Wp[(f0 + 2) * 3 + 1], s1);
      s2 = fmaf(v.z, Wp[(f0 + 2) * 3 + 2], s2);
      s0 = fmaf(v.w, Wp[(f0 + 3) * 3 + 0], s0);
      s1 = fmaf(v.w, Wp[(f0 + 3) * 3 + 1], s1);
      s2 = fmaf(v.w, Wp[(f0 + 3) * 3 + 2], s2);
    }
    waveRed3(s0, s1, s2);
    if (lane == 0) {
      Wcomb[row * 3 + 0] = s0; Wcomb[row * 3 + 1] = s1; Wcomb[row * 3 + 2] = s2;
    }
  } else if (blk < OFF_BC) {
    const int lane = tid & 63;
    const int b = (blk - OFF_RT) * 4 + (tid >> 6);
    const float* cls = hs + (size_t)b * S_ * H_;
    const int e = lane & 15, part = lane >> 4;
    float sum = 0.0f;
    for (int i = part * 256; i < part * 256 + 256; ++i)
      sum = fmaf(cls[i], Wr[i * E_ + e], sum);
    sum += __shfl_down(sum, 32);
    sum += __shfl_down(sum, 16);
    float lg[E_];
#pragma unroll
    for (int i = 0; i < E_; ++i) lg[i] = __shfl(sum, i);
    if (lane == 0) {
      for (int i = 0; i < E_; ++i) lg[i] += br[i];
      int idx[K_]; float tv[K_];
      for (int k = 0; k < K_; ++k) {
        int bi = 0; float bv = -1e30f;
        for (int i = 0; i < E_; ++i) { if (lg[i] > bv) { bv = lg[i]; bi = i; } }
        idx[k] = bi; tv[k] = bv; lg[bi] = -1e30f;
      }
      float mx = tv[0], ssum = 0.0f, p[K_];
      for (int k = 0; k < K_; ++k) { p[k] = expf(tv[k] - mx); ssum += p[k]; }
      for (int k = 0; k < K_; ++k) {
        p[k] /= ssum;
        topk_idx[b * K_ + k] = idx[k];
        topk_prob[b * K_ + k] = p[k];
        int pos = atomicAdd(&counts[idx[k]], 1);
        pairlist[idx[k] * B_ + pos] = b * K_ + k;
      }
    }
  } else {
    const int e = (blk - OFF_BC) * 4 + (tid >> 6);
    const int lane = tid & 63;
    const float* wrp = be2 + (size_t)e * HID_;
    float s0 = 0, s1 = 0, s2 = 0;
    for (int f = lane; f < HID_; f += 64) {
      float v = wrp[f];
      s0 = fmaf(v, Wp[f * 3 + 0], s0);
      s1 = fmaf(v, Wp[f * 3 + 1], s1);
      s2 = fmaf(v, Wp[f * 3 + 2], s2);
    }
    waveRed3(s0, s1, s2);
    if (lane == 0) {
      bcomb[e * 3 + 0] = s0 + bp[0]; bcomb[e * 3 + 1] = s1 + bp[1]; bcomb[e * 3 + 2] = s2 + bp[2];
    }
  }
}

// ---------------------------------------------------------------------------
// Phase B: unified MFMA GEMM (R13 structure). z<16: expert GEMM (A via
// gload_lds from m splits, B fp32->bf16 in-register from We1). z==16: cls@Wd
// with BOTH operands fp32->bf16 in-register (A from hs row 0 contiguous —
// R14's proven path; no cls splits needed). 128x128 tile, SPLIT-K=2, BK=32,
// race-fixed static dbuf + DMA_DRAIN.
// ---------------------------------------------------------------------------
__global__ __launch_bounds__(512) void gemm_mega(
    const float* __restrict__ hs,
    const ushort* __restrict__ m_hi, const ushort* __restrict__ m_lo,
    const float* __restrict__ Wd, const float* __restrict__ We1,
    const int* __restrict__ counts, const int* __restrict__ pairlist,
    float* __restrict__ tA, float* __restrict__ tB,
    float* __restrict__ h1A, float* __restrict__ h1B) {
  __shared__ __align__(16) ushort ldsAh0[4096], ldsAl0[4096], ldsBh0[4096], ldsBl0[4096];
  __shared__ __align__(16) ushort ldsAh1[4096], ldsAl1[4096], ldsBh1[4096], ldsBl1[4096];
  const int z = blockIdx.z;
  const int tid = threadIdx.x;
  const int lane = tid & 63, w = tid >> 6;          // w in 0..7
  const int mt = blockIdx.y >> 1, kh = blockIdx.y & 1;
  const int m0 = mt * 128, n0 = blockIdx.x * 128;
  const int kbase = kh * 512;
  const int wr = w >> 2, wc = w & 3;                 // compute role: 2x4 grid
  const int lr = (lane >> 4) << 2, lc = lane & 15;

  if (z == 16) {
    // ---- cls @ Wd: both operands fp32 -> in-register hi/lo split ----
    const float* sbase[2];
    size_t kstride;
    int subs0;
    if (w < 4) {
      kstride = 1;
      subs0 = w * 2;
#pragma unroll
      for (int sl = 0; sl < 2; ++sl) {
        int s = subs0 + sl;
        int b = m0 + s * 16 + (lane & 15);
        sbase[sl] = hs + (size_t)b * (S_ * H_) + ((lane >> 4) << 3);
      }
    } else {
      kstride = H_;
      subs0 = (w - 4) * 2;
#pragma unroll
      for (int sl = 0; sl < 2; ++sl) {
        int s = subs0 + sl;
        int col = n0 + s * 16 + (lane & 15);
        sbase[sl] = Wd + col + (size_t)((lane >> 4) << 3) * H_;
      }
    }
    f32x4 acc[4][2] = {};

    auto stage = [&](int kofs, ushort* dAh, ushort* dAl, ushort* dBh, ushort* dBl) {
      ushort* dh = (w < 4) ? dAh : dBh;
      ushort* dl = (w < 4) ? dAl : dBl;
#pragma unroll
      for (int sl = 0; sl < 2; ++sl) {
        const float* p = sbase[sl] + (size_t)kofs * kstride;
        float f[8];
        if (w < 4) {
          fvec4 v0 = nt_load4f(p);
          fvec4 v1 = nt_load4f(p + 4);
          f[0] = v0.x; f[1] = v0.y; f[2] = v0.z; f[3] = v0.w;
          f[4] = v1.x; f[5] = v1.y; f[6] = v1.z; f[7] = v1.w;
        } else {
#pragma unroll
          for (int j = 0; j < 8; ++j) f[j] = p[(size_t)j * H_];
        }
        usvec8 vh, vl;
#pragma unroll
        for (int j = 0; j < 8; ++j) {
          ushort hi, lo;
          split2(f[j], hi, lo);
          vh[j] = hi; vl[j] = lo;
        }
        const int off = (subs0 + sl) * 512 + lane * 8;
        *(usvec8*)&dh[off] = vh;
        *(usvec8*)&dl[off] = vl;
      }
    };
    auto compute = [&](const ushort* Ah, const ushort* Al,
                       const ushort* Bh, const ushort* Bl) {
      bf16x8 ah[4], al[4], bh[2], bl[2];
#pragma unroll
      for (int i = 0; i < 4; ++i) {
        int off = (wr * 4 + i) * 512 + lane * 8;
        ah[i] = *(const bf16x8*)&Ah[off];
        al[i] = *(const bf16x8*)&Al[off];
      }
#pragma unroll
      for (int j = 0; j < 2; ++j) {
        int off = (wc * 2 + j) * 512 + lane * 8;
        bh[j] = *(const bf16x8*)&Bh[off];
        bl[j] = *(const bf16x8*)&Bl[off];
      }
#pragma unroll
      for (int i = 0; i < 4; ++i)
#pragma unroll
        for (int j = 0; j < 2; ++j) {
          acc[i][j] = __builtin_amdgcn_mfma_f32_16x16x32_bf16(ah[i], bh[j], acc[i][j], 0, 0, 0);
          acc[i][j] = __builtin_amdgcn_mfma_f32_16x16x32_bf16(ah[i], bl[j], acc[i][j], 0, 0, 0);
          acc[i][j] = __builtin_amdgcn_mfma_f32_16x16x32_bf16(al[i], bh[j], acc[i][j], 0, 0, 0);
        }
    };

    stage(kbase, ldsAh0, ldsAl0, ldsBh0, ldsBl0);
    DMA_DRAIN();
    __syncthreads();
#pragma unroll 1
    for (int tt = 0; tt < 8; ++tt) {
      const int t0 = tt * 2;
      stage(kbase + (t0 + 1) * 32, ldsAh1, ldsAl1, ldsBh1, ldsBl1);
      compute(ldsAh0, ldsAl0, ldsBh0, ldsBl0);
      DMA_DRAIN();
      __syncthreads();
      if (tt < 7) stage(kbase + (t0 + 2) * 32, ldsAh0, ldsAl0, ldsBh0, ldsBl0);
      compute(ldsAh1, ldsAl1, ldsBh1, ldsBl1);
      DMA_DRAIN();
      __syncthreads();
    }
    float* tp = kh ? tB : tA;
#pragma unroll
    for (int i = 0; i < 4; ++i) {
      int row = m0 + wr * 64 + i * 16 + lr;
#pragma unroll
      for (int j = 0; j < 2; ++j) {
        int col = n0 + wc * 32 + j * 16 + lc;
#pragma unroll
        for (int r = 0; r < 4; ++r)
          nt_store1f(&tp[(size_t)(row + r) * H_ + col], acc[i][j][r]);
      }
    }
    return;
  }

  // ---- expert GEMM (R13 verbatim) ----
  const int n_e = counts[z];
  if (m0 >= n_e) return;

  const ushort* srcp[4];
  ushort* dstA0 = nullptr; ushort* dstA1 = nullptr;
  const float* bbase[2];
  int bsub[2];
  const int halfq = w & 1;
  if (w < 4) {
    const int warr = w >> 1;
    dstA0 = (warr == 0) ? ldsAh0 : ldsAl0;
    dstA1 = (warr == 0) ? ldsAh1 : ldsAl1;
    const ushort* sbase = (warr == 0) ? m_hi : m_lo;
#pragma unroll
    for (int sl = 0; sl < 4; ++sl) {
      int s = halfq * 4 + sl;
      int r = m0 + s * 16 + (lane & 15);
      if (r >= n_e) r = n_e - 1;
      r = pairlist[z * B_ + r] >> 2;
      srcp[sl] = sbase + (size_t)r * H_ + ((lane >> 4) << 3);
    }
  } else {
    const float* Wfp = We1 + (size_t)z * H_ * HID_;
#pragma unroll
    for (int sl = 0; sl < 2; ++sl) {
      int s = (w - 4) * 2 + sl;
      bsub[sl] = s;
      int col = n0 + s * 16 + (lane & 15);
      bbase[sl] = Wfp + col + (size_t)((lane >> 4) << 3) * HID_;
    }
  }

  f32x4 acc[4][2] = {};

  auto stageA = [&](int kofs, ushort* dst) {
#pragma unroll
    for (int sl = 0; sl < 4; ++sl)
      gload_lds16(srcp[sl] + kofs, dst + (halfq * 4 + sl) * 512);
  };
  auto stageB = [&](int kofs, ushort* dBh, ushort* dBl) {
#pragma unroll
    for (int sl = 0; sl < 2; ++sl) {
      const float* bp = bbase[sl] + (size_t)kofs * HID_;
      float f[8];
#pragma unroll
      for (int j = 0; j < 8; ++j) f[j] = bp[(size_t)j * HID_];
      usvec8 vh, vl;
#pragma unroll
      for (int j = 0; j < 8; ++j) {
        ushort hi, lo;
        split2(f[j], hi, lo);
        vh[j] = hi; vl[j] = lo;
      }
      const int off = bsub[sl] * 512 + lane * 8;
      *(usvec8*)&dBh[off] = vh;
      *(usvec8*)&dBl[off] = vl;
    }
  };
  auto stage_buf0 = [&](int kofs) {
    if (w < 4) stageA(kofs, dstA0);
    else stageB(kofs, ldsBh0, ldsBl0);
  };
  auto stage_buf1 = [&](int kofs) {
    if (w < 4) stageA(kofs, dstA1);
    else stageB(kofs, ldsBh1, ldsBl1);
  };
  auto compute = [&](const ushort* Ah, const ushort* Al,
                     const ushort* Bh, const ushort* Bl) {
    bf16x8 ah[4], al[4], bh[2], bl[2];
#pragma unroll
    for (int i = 0; i < 4; ++i) {
      int off = (wr * 4 + i) * 512 + lane * 8;
      ah[i] = *(const bf16x8*)&Ah[off];
      al[i] = *(const bf16x8*)&Al[off];
    }
#pragma unroll
    for (int j = 0; j < 2; ++j) {
      int off = (wc * 2 + j) * 512 + lane * 8;
      bh[j] = *(const bf16x8*)&Bh[off];
      bl[j] = *(const bf16x8*)&Bl[off];
    }
#pragma unroll
    for (int i = 0; i < 4; ++i)
#pragma unroll
      for (int j = 0; j < 2; ++j) {
        acc[i][j] = __builtin_amdgcn_mfma_f32_16x16x32_bf16(ah[i], bh[j], acc[i][j], 0, 0, 0);
        acc[i][j] = __builtin_amdgcn_mfma_f32_16x16x32_bf16(ah[i], bl[j], acc[i][j], 0, 0, 0);
        acc[i][j] = __builtin_amdgcn_mfma_f32_16x16x32_bf16(al[i], bh[j], acc[i][j], 0, 0, 0);
      }
  };

  stage_buf0(kbase);
  DMA_DRAIN();
  __syncthreads();
#pragma unroll 1
  for (int tt = 0; tt < 8; ++tt) {
    const int t0 = tt * 2;
    stage_buf1(kbase + (t0 + 1) * 32);
    compute(ldsAh0, ldsAl0, ldsBh0, ldsBl0);
    DMA_DRAIN();
    __syncthreads();
    if (tt < 7) stage_buf0(kbase + (t0 + 2) * 32);
    compute(ldsAh1, ldsAl1, ldsBh1, ldsBl1);
    DMA_DRAIN();
    __syncthreads();
  }

  float* hp = kh ? h1B : h1A;
#pragma unroll
  for (int i = 0; i < 4; ++i) {
    int pr[4]; bool ok[4];
#pragma unroll
    for (int r = 0; r < 4; ++r) {
      int li = m0 + wr * 64 + i * 16 + lr + r;
      ok[r] = li < n_e;
      pr[r] = pairlist[z * B_ + (ok[r] ? li : n_e - 1)];
    }
#pragma unroll
    for (int j = 0; j < 2; ++j) {
      int col = n0 + wc * 32 + j * 16 + lc;
#pragma unroll
      for (int r = 0; r < 4; ++r)
        if (ok[r]) nt_store1f(&hp[(size_t)pr[r] * HID_ + col], acc[i][j][r]);
    }
  }
}

// ---------------------------------------------------------------------------
// Phase C: fused epilogue (unchanged). One block per sample b.
// ---------------------------------------------------------------------------
__global__ __launch_bounds__(256) void epi_kernel(
    const float* __restrict__ tA, const float* __restrict__ tB,
    const float* __restrict__ bd,
    const float* __restrict__ Wo, const float* __restrict__ bo,
    const float* __restrict__ h1A, const float* __restrict__ h1B,
    const float* __restrict__ be1,
    const float* __restrict__ g1, const float* __restrict__ beta1,
    const int* __restrict__ topk_idx, const float* __restrict__ topk_prob,
    const float* __restrict__ Wcomb, const float* __restrict__ bcomb,
    const float* __restrict__ Wf1, const float* __restrict__ bf1,
    const float* __restrict__ gf, const float* __restrict__ betaf,
    const float* __restrict__ Wf2, const float* __restrict__ bf2,
    float* __restrict__ out) {
  const int b = blockIdx.x;
  const int tid = threadIdx.x;
  const int w = tid >> 6, lane = tid & 63;
  __shared__ float sCtr[4][3];
  __shared__ float sOl[4][3];

  const int pair = b * K_ + w;
  const int e = topk_idx[pair];
  const float prob = topk_prob[pair];
  const float* hrA = h1A + (size_t)pair * HID_;
  const float* hrB = h1B + (size_t)pair * HID_;
  const float* ber = be1 + (size_t)e * HID_;
  float x[4][4];
#pragma unroll
  for (int q = 0; q < 4; ++q) {
    const int d = q * 256 + lane * 4;
    fvec4 a = nt_load4f(&hrA[d]);
    fvec4 bq = nt_load4f(&hrB[d]);
    float4 be = *(const float4*)&ber[d];
    x[q][0] = a.x + bq.x + be.x; x[q][1] = a.y + bq.y + be.y;
    x[q][2] = a.z + bq.z + be.z; x[q][3] = a.w + bq.w + be.w;
  }
  float s = 0;
#pragma unroll
  for (int q = 0; q < 4; ++q) s += x[q][0] + x[q][1] + x[q][2] + x[q][3];
#pragma unroll
  for (int off = 32; off; off >>= 1) s += __shfl_down(s, off);
  const float mu = __shfl(s, 0) * (1.0f / HID_);
  float sq = 0;
#pragma unroll
  for (int q = 0; q < 4; ++q)
#pragma unroll
    for (int i = 0; i < 4; ++i) {
      float d = x[q][i] - mu;
      sq += d * d;
    }
#pragma unroll
  for (int off = 32; off; off >>= 1) sq += __shfl_down(sq, off);
  const float inv = 1.0f / sqrtf(__shfl(sq, 0) * (1.0f / HID_) + EPS_);
  float c0 = 0, c1 = 0, c2 = 0;
#pragma unroll
  for (int q = 0; q < 4; ++q) {
    const int d = q * 256 + lane * 4;
    float4 gg = *(const float4*)&g1[(size_t)e * HID_ + d];
    float4 bb = *(const float4*)&beta1[(size_t)e * HID_ + d];
    float gv[4] = {gg.x, gg.y, gg.z, gg.w};
    float bv[4] = {bb.x, bb.y, bb.z, bb.w};
#pragma unroll
    for (int i = 0; i < 4; ++i) {
      float v = (x[q][i] - mu) * inv * gv[i] + bv[i];
      v = 0.5f * v * (1.0f + erff(v * 0.70710678118654752440f));  // exact gelu
      const float* wc = &Wcomb[(size_t)(e * HID_ + d + i) * 3];
      c0 = fmaf(v, wc[0], c0); c1 = fmaf(v, wc[1], c1); c2 = fmaf(v, wc[2], c2);
    }
  }
  waveRed3(c0, c1, c2);
  if (lane == 0) {
    sCtr[w][0] = prob * (c0 + bcomb[e * 3 + 0]);
    sCtr[w][1] = prob * (c1 + bcomb[e * 3 + 1]);
    sCtr[w][2] = prob * (c2 + bcomb[e * 3 + 2]);
  }

  {
    const int h0 = w * 256 + lane * 4;
    fvec4 ta = nt_load4f(&tA[(size_t)b * H_ + h0]);
    fvec4 tb = nt_load4f(&tB[(size_t)b * H_ + h0]);
    float4 bdv = *(const float4*)&bd[h0];
    float tvv[4] = {tanhf(ta.x + tb.x + bdv.x), tanhf(ta.y + tb.y + bdv.y),
                    tanhf(ta.z + tb.z + bdv.z), tanhf(ta.w + tb.w + bdv.w)};
    float o0 = 0, o1 = 0, o2 = 0;
#pragma unroll
    for (int i = 0; i < 4; ++i) {
      const float* wo = &Wo[(size_t)(h0 + i) * 3];
      o0 = fmaf(tvv[i], wo[0], o0); o1 = fmaf(tvv[i], wo[1], o1); o2 = fmaf(tvv[i], wo[2], o2);
    }
    waveRed3(o0, o1, o2);
    if (lane == 0) { sOl[w][0] = o0; sOl[w][1] = o1; sOl[w][2] = o2; }
  }
  __syncthreads();

  if (tid == 0) {
    float comb[6];
#pragma unroll
    for (int c = 0; c < 3; ++c) {
      comb[c] = sOl[0][c] + sOl[1][c] + sOl[2][c] + sOl[3][c] + bo[c];
      comb[3 + c] = sCtr[0][c] + sCtr[1][c] + sCtr[2][c] + sCtr[3][c];
    }
    float z[3];
#pragma unroll
    for (int c = 0; c < 3; ++c) {
      float sv = bf1[c];
#pragma unroll
      for (int i = 0; i < 6; ++i) sv = fmaf(comb[i], Wf1[i * 3 + c], sv);
      z[c] = sv;
    }
    float mu3 = (z[0] + z[1] + z[2]) * (1.0f / 3.0f);
    float v0 = z[0] - mu3, v1 = z[1] - mu3, v2 = z[2] - mu3;
    float var = (v0 * v0 + v1 * v1 + v2 * v2) * (1.0f / 3.0f);
    float inv3 = 1.0f / sqrtf(var + EPS_);
    float r[3];
#pragma unroll
    for (int c = 0; c < 3; ++c) {
      float zz = (z[c] - mu3) * inv3 * gf[c] + betaf[c];
      r[c] = zz > 0.0f ? zz : 0.0f;
    }
#pragma unroll
    for (int c = 0; c < 3; ++c) {
      float sv = bf2[c];
#pragma unroll
      for (int i = 0; i < 3; ++i) sv = fmaf(r[i], Wf2[i * 3 + c], sv);
      out[b * 3 + c] = sv;
    }
  }
}

// ---------------------------------------------------------------------------
extern "C" void kernel_launch(void* const* d_in, const int* in_sizes, int n_in,
                              void* d_out, int out_size, void* d_ws, size_t ws_size,
                              hipStream_t stream) {
  const float* hs    = (const float*)d_in[0];
  const float* Wd    = (const float*)d_in[1];
  const float* bd    = (const float*)d_in[2];
  const float* Wo    = (const float*)d_in[3];
  const float* bo    = (const float*)d_in[4];
  const float* Wr    = (const float*)d_in[5];
  const float* br    = (const float*)d_in[6];
  const float* We1   = (const float*)d_in[7];
  const float* be1   = (const float*)d_in[8];
  const float* g1    = (const float*)d_in[9];
  const float* beta1 = (const float*)d_in[10];
  const float* We2   = (const float*)d_in[11];
  const float* be2   = (const float*)d_in[12];
  const float* Wp    = (const float*)d_in[13];
  const float* bp    = (const float*)d_in[14];
  const float* Wf1   = (const float*)d_in[15];
  const float* bf1   = (const float*)d_in[16];
  const float* gf    = (const float*)d_in[17];
  const float* betaf = (const float*)d_in[18];
  const float* Wf2   = (const float*)d_in[19];
  const float* bf2   = (const float*)d_in[20];
  float* out = (float*)d_out;

  char* w = (char*)d_ws;
  size_t off = 0;
  auto alloc = [&](size_t bytes) {
    void* p = w + off;
    off = (off + bytes + 255) & ~(size_t)255;
    return p;
  };
  ushort* m_hi   = (ushort*)alloc((size_t)B_ * H_ * 2);
  ushort* m_lo   = (ushort*)alloc((size_t)B_ * H_ * 2);
  float* ws_tA   = (float*)alloc((size_t)B_ * H_ * 4);
  float* ws_tB   = (float*)alloc((size_t)B_ * H_ * 4);
  float* ws_h1A  = (float*)alloc((size_t)B_ * K_ * HID_ * 4);
  float* ws_h1B  = (float*)alloc((size_t)B_ * K_ * HID_ * 4);
  float* ws_wc   = (float*)alloc((size_t)E_ * HID_ * 3 * 4);
  float* ws_bc   = (float*)alloc(E_ * 3 * 4);
  float* ws_prob = (float*)alloc(B_ * K_ * 4);
  int* ws_idx = (int*)alloc(B_ * K_ * 4);
  int* ws_cnt = (int*)alloc(E_ * 4);
  int* ws_pl  = (int*)alloc(E_ * B_ * 4);
  if (off > ws_size) return;

  hipMemsetAsync(ws_cnt, 0, E_ * sizeof(int), stream);

  prep_kernel<<<NB_PREP, 256, 0, stream>>>(hs, We2, Wp, bp, Wr, br, be2,
                                           m_hi, m_lo, ws_wc, ws_bc,
                                           ws_idx, ws_prob, ws_cnt, ws_pl);
  gemm_mega<<<dim3(8, 16, 17), 512, 0, stream>>>(hs, m_hi, m_lo, Wd, We1,
                                                 ws_cnt, ws_pl,
                                                 ws_tA, ws_tB, ws_h1A, ws_h1B);
  epi_kernel<<<B_, 256, 0, stream>>>(ws_tA, ws_tB, bd, Wo, bo, ws_h1A, ws_h1B, be1,
                                     g1, beta1, ws_idx, ws_prob, ws_wc, ws_bc,
                                     Wf1, bf1, gf, betaf, Wf2, bf2, out);
}

// Round 18
// 231.097 us; speedup vs baseline: 1.1116x; 1.0945x over previous
//
#include <hip/hip_runtime.h>
#include <math.h>

#define B_ 1024
#define S_ 128
#define H_ 1024
#define E_ 16
#define HID_ 1024
#define K_ 4
#define C_ 3
#define EPS_ 1e-5f

// prep kernel segment offsets (weight-split segments REMOVED — the GEMM
// converts B fp32->bf16 hi/lo in-register from the original K-major weights)
#define NB_MEAN 1024
#define NB_WC 4096
#define NB_RT 256
#define NB_BC 4
#define OFF_WC (NB_MEAN)
#define OFF_RT (OFF_WC + NB_WC)
#define OFF_BC (OFF_RT + NB_RT)
#define NB_PREP (OFF_BC + NB_BC)

typedef __attribute__((ext_vector_type(8))) __bf16 bf16x8;
typedef __attribute__((ext_vector_type(4))) float f32x4;
typedef __attribute__((ext_vector_type(4))) float fvec4;
typedef __attribute__((ext_vector_type(4))) unsigned short usvec4;
typedef __attribute__((ext_vector_type(8))) unsigned short usvec8;

__device__ __forceinline__ ushort bf16_rn(float f) {
  unsigned u = __float_as_uint(f);
  u += 0x7FFF + ((u >> 16) & 1);
  return (ushort)(u >> 16);
}
__device__ __forceinline__ float bf16_to_f(ushort h) {
  return __uint_as_float(((unsigned)h) << 16);
}
__device__ __forceinline__ void split2(float f, ushort& h, ushort& l) {
  h = bf16_rn(f);
  l = bf16_rn(f - bf16_to_f(h));
}
__device__ __forceinline__ void gload_lds16(const void* g, void* l) {
  __builtin_amdgcn_global_load_lds((const __attribute__((address_space(1))) void*)g,
                                   (__attribute__((address_space(3))) void*)l, 16, 0, 0);
}
// Explicit LDS-DMA drain (rule #18: asm waitcnt + sched_barrier(0)).
#define DMA_DRAIN() do {                                  \
    asm volatile("s_waitcnt vmcnt(0)" ::: "memory");      \
    __builtin_amdgcn_sched_barrier(0);                    \
  } while (0)

// nontemporal shims — ONLY for true stream-once data.
__device__ __forceinline__ fvec4 nt_load4f(const float* p) {
  return __builtin_nontemporal_load((const fvec4*)p);
}
__device__ __forceinline__ void st4us(ushort* p, ushort a, ushort b, ushort c, ushort d) {
  usvec4 v; v.x = a; v.y = b; v.z = c; v.w = d;
  *(usvec4*)p = v;
}
__device__ __forceinline__ void nt_store1f(float* p, float v) {
  __builtin_nontemporal_store(v, p);
}
__device__ __forceinline__ void waveRed3(float& s0, float& s1, float& s2) {
#pragma unroll
  for (int off = 32; off; off >>= 1) {
    s0 += __shfl_down(s0, off); s1 += __shfl_down(s1, off); s2 += __shfl_down(s2, off);
  }
}

// ---------------------------------------------------------------------------
// Phase A: prep — mean/cls splits, Wcomb, router, bcomb. (No weight splits.)
// ---------------------------------------------------------------------------
__global__ __launch_bounds__(256) void prep_kernel(
    const float* __restrict__ hs,
    const float* __restrict__ We2, const float* __restrict__ Wp, const float* __restrict__ bp,
    const float* __restrict__ Wr, const float* __restrict__ br,
    const float* __restrict__ be2,
    ushort* __restrict__ m_hi, ushort* __restrict__ m_lo,
    ushort* __restrict__ cls_hi, ushort* __restrict__ cls_lo,
    float* __restrict__ Wcomb, float* __restrict__ bcomb,
    int* __restrict__ topk_idx, float* __restrict__ topk_prob,
    int* __restrict__ counts, int* __restrict__ pairlist) {
  const int blk = blockIdx.x;
  const int tid = threadIdx.x;

  if (blk < NB_MEAN) {
    int gid = blk * 256 + tid;
    int b = gid >> 8;
    int h4 = (gid & 255) << 2;
    const float* p = hs + (size_t)b * S_ * H_ + h4;
    fvec4 v0 = nt_load4f(p);
    float sx = v0.x, sy = v0.y, sz = v0.z, sw = v0.w;
#pragma unroll 8
    for (int s = 1; s < S_; ++s) {
      fvec4 v = nt_load4f(p + (size_t)s * H_);
      sx += v.x; sy += v.y; sz += v.z; sw += v.w;
    }
    const float inv = 1.0f / (float)S_;
    float mv[4] = {sx * inv, sy * inv, sz * inv, sw * inv};
    float cv[4] = {v0.x, v0.y, v0.z, v0.w};
    ushort mh[4], ml[4], ch[4], cl[4];
#pragma unroll
    for (int i = 0; i < 4; ++i) { split2(mv[i], mh[i], ml[i]); split2(cv[i], ch[i], cl[i]); }
    size_t o = (size_t)b * H_ + h4;
    st4us(&m_hi[o], mh[0], mh[1], mh[2], mh[3]);
    st4us(&m_lo[o], ml[0], ml[1], ml[2], ml[3]);
    st4us(&cls_hi[o], ch[0], ch[1], ch[2], ch[3]);
    st4us(&cls_lo[o], cl[0], cl[1], cl[2], cl[3]);
  } else if (blk < OFF_RT) {
    // ---- Wcomb[row,:] = We2[row,:] @ Wp — float4 loads ----
    const int row = (blk - OFF_WC) * 4 + (tid >> 6);
    const int lane = tid & 63;
    const float* wrp = We2 + (size_t)row * HID_;
    float s0 = 0, s1 = 0, s2 = 0;
#pragma unroll
    for (int it = 0; it < 4; ++it) {
      const int f0 = it * 256 + lane * 4;
      fvec4 v = nt_load4f(&wrp[f0]);
      s0 = fmaf(v.x, Wp[(f0 + 0) * 3 + 0], s0);
      s1 = fmaf(v.x, Wp[(f0 + 0) * 3 + 1], s1);
      s2 = fmaf(v.x, Wp[(f0 + 0) * 3 + 2], s2);
      s0 = fmaf(v.y, Wp[(f0 + 1) * 3 + 0], s0);
      s1 = fmaf(v.y, Wp[(f0 + 1) * 3 + 1], s1);
      s2 = fmaf(v.y, Wp[(f0 + 1) * 3 + 2], s2);
      s0 = fmaf(v.z, Wp[(f0 + 2) * 3 + 0], s0);
      s1 = fmaf(v.z, Wp[(f0 + 2) * 3 + 1], s1);
      s2 = fmaf(v.z, Wp[(f0 + 2) * 3 + 2], s2);
      s0 = fmaf(v.w, Wp[(f0 + 3) * 3 + 0], s0);
      s1 = fmaf(v.w, Wp[(f0 + 3) * 3 + 1], s1);
      s2 = fmaf(v.w, Wp[(f0 + 3) * 3 + 2], s2);
    }
    waveRed3(s0, s1, s2);
    if (lane == 0) {
      Wcomb[row * 3 + 0] = s0; Wcomb[row * 3 + 1] = s1; Wcomb[row * 3 + 2] = s2;
    }
  } else if (blk < OFF_BC) {
    const int lane = tid & 63;
    const int b = (blk - OFF_RT) * 4 + (tid >> 6);
    const float* cls = hs + (size_t)b * S_ * H_;
    const int e = lane & 15, part = lane >> 4;
    float sum = 0.0f;
    for (int i = part * 256; i < part * 256 + 256; ++i)
      sum = fmaf(cls[i], Wr[i * E_ + e], sum);
    sum += __shfl_down(sum, 32);
    sum += __shfl_down(sum, 16);
    float lg[E_];
#pragma unroll
    for (int i = 0; i < E_; ++i) lg[i] = __shfl(sum, i);
    if (lane == 0) {
      for (int i = 0; i < E_; ++i) lg[i] += br[i];
      int idx[K_]; float tv[K_];
      for (int k = 0; k < K_; ++k) {
        int bi = 0; float bv = -1e30f;
        for (int i = 0; i < E_; ++i) { if (lg[i] > bv) { bv = lg[i]; bi = i; } }
        idx[k] = bi; tv[k] = bv; lg[bi] = -1e30f;
      }
      float mx = tv[0], ssum = 0.0f, p[K_];
      for (int k = 0; k < K_; ++k) { p[k] = expf(tv[k] - mx); ssum += p[k]; }
      for (int k = 0; k < K_; ++k) {
        p[k] /= ssum;
        topk_idx[b * K_ + k] = idx[k];
        topk_prob[b * K_ + k] = p[k];
        int pos = atomicAdd(&counts[idx[k]], 1);
        pairlist[idx[k] * B_ + pos] = b * K_ + k;
      }
    }
  } else {
    const int e = (blk - OFF_BC) * 4 + (tid >> 6);
    const int lane = tid & 63;
    const float* wrp = be2 + (size_t)e * HID_;
    float s0 = 0, s1 = 0, s2 = 0;
    for (int f = lane; f < HID_; f += 64) {
      float v = wrp[f];
      s0 = fmaf(v, Wp[f * 3 + 0], s0);
      s1 = fmaf(v, Wp[f * 3 + 1], s1);
      s2 = fmaf(v, Wp[f * 3 + 2], s2);
    }
    waveRed3(s0, s1, s2);
    if (lane == 0) {
      bcomb[e * 3 + 0] = s0 + bp[0]; bcomb[e * 3 + 1] = s1 + bp[1]; bcomb[e * 3 + 2] = s2 + bp[2];
    }
  }
}

// ---------------------------------------------------------------------------
// Phase B: unified MFMA GEMM — 512 thr / 8 waves, 128x128 tile, SPLIT-K=2,
// BK=32, race-fixed 2-phase dbuf (static buffers + DMA_DRAIN). B-operand is
// converted fp32->bf16 hi/lo IN-REGISTER from the ORIGINAL K-major weights
// (Wd / We1) by waves 4-7 (2 subtiles each); waves 0-3 stage A via
// global_load_lds from the m/cls splits. (Best-measured config: 231.5 us.)
// ---------------------------------------------------------------------------
__global__ __launch_bounds__(512) void gemm_mega(
    const ushort* __restrict__ m_hi, const ushort* __restrict__ m_lo,
    const ushort* __restrict__ cls_hi, const ushort* __restrict__ cls_lo,
    const float* __restrict__ Wd, const float* __restrict__ We1,
    const int* __restrict__ counts, const int* __restrict__ pairlist,
    float* __restrict__ tA, float* __restrict__ tB,
    float* __restrict__ h1A, float* __restrict__ h1B) {
  __shared__ __align__(16) ushort ldsAh0[4096], ldsAl0[4096], ldsBh0[4096], ldsBl0[4096];
  __shared__ __align__(16) ushort ldsAh1[4096], ldsAl1[4096], ldsBh1[4096], ldsBl1[4096];
  const int z = blockIdx.z;
  const int tid = threadIdx.x;
  const int lane = tid & 63, w = tid >> 6;          // w in 0..7
  const int mt = blockIdx.y >> 1, kh = blockIdx.y & 1;
  const int m0 = mt * 128, n0 = blockIdx.x * 128;
  const int kbase = kh * 512;
  int n_e;
  if (z == 16) n_e = B_;
  else { n_e = counts[z]; if (m0 >= n_e) return; }

  // ---- staging-role setup ----
  const ushort* srcp[4];        // A waves (w<4): 4 subtiles via gload_lds
  ushort* dstA0 = nullptr; ushort* dstA1 = nullptr;
  const float* bbase[2];        // B waves (w>=4): 2 subtiles, fp32 strided
  int bsub[2];
  const int halfq = w & 1;
  if (w < 4) {
    const int warr = w >> 1;    // 0 = A_hi, 1 = A_lo
    dstA0 = (warr == 0) ? ldsAh0 : ldsAl0;
    dstA1 = (warr == 0) ? ldsAh1 : ldsAl1;
    const ushort* sbase;
    if (z == 16) sbase = (warr == 0) ? cls_hi : cls_lo;
    else         sbase = (warr == 0) ? m_hi  : m_lo;
#pragma unroll
    for (int sl = 0; sl < 4; ++sl) {
      int s = halfq * 4 + sl;
      int r = m0 + s * 16 + (lane & 15);
      if (z != 16) {
        if (r >= n_e) r = n_e - 1;
        r = pairlist[z * B_ + r] >> 2;      // sample index
      }
      srcp[sl] = sbase + (size_t)r * H_ + ((lane >> 4) << 3);
    }
  } else {
    const float* Wfp = (z == 16) ? Wd : (We1 + (size_t)z * H_ * HID_);
#pragma unroll
    for (int sl = 0; sl < 2; ++sl) {
      int s = (w - 4) * 2 + sl;
      bsub[sl] = s;
      int col = n0 + s * 16 + (lane & 15);
      bbase[sl] = Wfp + col + (size_t)(lane >> 4) * 8 * HID_;
    }
  }

  const int wr = w >> 2, wc = w & 3;                 // compute role: 2x4 grid
  f32x4 acc[4][2] = {};

  auto stageA = [&](int kofs, ushort* dst) {
#pragma unroll
    for (int sl = 0; sl < 4; ++sl)
      gload_lds16(srcp[sl] + kofs, dst + (halfq * 4 + sl) * 512);
  };
  auto stageB = [&](int kofs, ushort* dBh, ushort* dBl) {
#pragma unroll
    for (int sl = 0; sl < 2; ++sl) {
      const float* bp = bbase[sl] + (size_t)kofs * HID_;
      float f[8];
#pragma unroll
      for (int j = 0; j < 8; ++j) f[j] = bp[(size_t)j * HID_];
      usvec8 vh, vl;
#pragma unroll
      for (int j = 0; j < 8; ++j) {
        ushort hi, lo;
        split2(f[j], hi, lo);
        vh[j] = hi; vl[j] = lo;
      }
      const int off = bsub[sl] * 512 + lane * 8;
      *(usvec8*)&dBh[off] = vh;
      *(usvec8*)&dBl[off] = vl;
    }
  };
  auto stage_buf0 = [&](int kofs) {
    if (w < 4) stageA(kofs, dstA0);
    else stageB(kofs, ldsBh0, ldsBl0);
  };
  auto stage_buf1 = [&](int kofs) {
    if (w < 4) stageA(kofs, dstA1);
    else stageB(kofs, ldsBh1, ldsBl1);
  };
  auto compute = [&](const ushort* Ah, const ushort* Al,
                     const ushort* Bh, const ushort* Bl) {
    bf16x8 ah[4], al[4], bh[2], bl[2];
#pragma unroll
    for (int i = 0; i < 4; ++i) {
      int off = (wr * 4 + i) * 512 + lane * 8;
      ah[i] = *(const bf16x8*)&Ah[off];
      al[i] = *(const bf16x8*)&Al[off];
    }
#pragma unroll
    for (int j = 0; j < 2; ++j) {
      int off = (wc * 2 + j) * 512 + lane * 8;
      bh[j] = *(const bf16x8*)&Bh[off];
      bl[j] = *(const bf16x8*)&Bl[off];
    }
#pragma unroll
    for (int i = 0; i < 4; ++i)
#pragma unroll
      for (int j = 0; j < 2; ++j) {
        acc[i][j] = __builtin_amdgcn_mfma_f32_16x16x32_bf16(ah[i], bh[j], acc[i][j], 0, 0, 0);
        acc[i][j] = __builtin_amdgcn_mfma_f32_16x16x32_bf16(ah[i], bl[j], acc[i][j], 0, 0, 0);
        acc[i][j] = __builtin_amdgcn_mfma_f32_16x16x32_bf16(al[i], bh[j], acc[i][j], 0, 0, 0);
      }
  };

  stage_buf0(kbase);
  DMA_DRAIN();
  __syncthreads();

#pragma unroll 1
  for (int tt = 0; tt < 8; ++tt) {
    const int t0 = tt * 2;
    stage_buf1(kbase + (t0 + 1) * 32);
    compute(ldsAh0, ldsAl0, ldsBh0, ldsBl0);
    DMA_DRAIN();
    __syncthreads();
    if (tt < 7) stage_buf0(kbase + (t0 + 2) * 32);
    compute(ldsAh1, ldsAl1, ldsBh1, ldsBl1);
    DMA_DRAIN();
    __syncthreads();
  }

  const int lr = (lane >> 4) << 2, lc = lane & 15;
  if (z == 16) {
    float* tp = kh ? tB : tA;
#pragma unroll
    for (int i = 0; i < 4; ++i) {
      int row = m0 + wr * 64 + i * 16 + lr;
#pragma unroll
      for (int j = 0; j < 2; ++j) {
        int col = n0 + wc * 32 + j * 16 + lc;
#pragma unroll
        for (int r = 0; r < 4; ++r)
          nt_store1f(&tp[(size_t)(row + r) * H_ + col], acc[i][j][r]);
      }
    }
  } else {
    float* hp = kh ? h1B : h1A;
#pragma unroll
    for (int i = 0; i < 4; ++i) {
      int pr[4]; bool ok[4];
#pragma unroll
      for (int r = 0; r < 4; ++r) {
        int li = m0 + wr * 64 + i * 16 + lr + r;
        ok[r] = li < n_e;
        pr[r] = pairlist[z * B_ + (ok[r] ? li : n_e - 1)];
      }
#pragma unroll
      for (int j = 0; j < 2; ++j) {
        int col = n0 + wc * 32 + j * 16 + lc;
#pragma unroll
        for (int r = 0; r < 4; ++r)
          if (ok[r]) nt_store1f(&hp[(size_t)pr[r] * HID_ + col], acc[i][j][r]);
      }
    }
  }
}

// ---------------------------------------------------------------------------
// Phase C: fused epilogue (unchanged). One block per sample b.
// ---------------------------------------------------------------------------
__global__ __launch_bounds__(256) void epi_kernel(
    const float* __restrict__ tA, const float* __restrict__ tB,
    const float* __restrict__ bd,
    const float* __restrict__ Wo, const float* __restrict__ bo,
    const float* __restrict__ h1A, const float* __restrict__ h1B,
    const float* __restrict__ be1,
    const float* __restrict__ g1, const float* __restrict__ beta1,
    const int* __restrict__ topk_idx, const float* __restrict__ topk_prob,
    const float* __restrict__ Wcomb, const float* __restrict__ bcomb,
    const float* __restrict__ Wf1, const float* __restrict__ bf1,
    const float* __restrict__ gf, const float* __restrict__ betaf,
    const float* __restrict__ Wf2, const float* __restrict__ bf2,
    float* __restrict__ out) {
  const int b = blockIdx.x;
  const int tid = threadIdx.x;
  const int w = tid >> 6, lane = tid & 63;
  __shared__ float sCtr[4][3];
  __shared__ float sOl[4][3];

  const int pair = b * K_ + w;
  const int e = topk_idx[pair];
  const float prob = topk_prob[pair];
  const float* hrA = h1A + (size_t)pair * HID_;
  const float* hrB = h1B + (size_t)pair * HID_;
  const float* ber = be1 + (size_t)e * HID_;
  float x[4][4];
#pragma unroll
  for (int q = 0; q < 4; ++q) {
    const int d = q * 256 + lane * 4;
    fvec4 a = nt_load4f(&hrA[d]);
    fvec4 bq = nt_load4f(&hrB[d]);
    float4 be = *(const float4*)&ber[d];
    x[q][0] = a.x + bq.x + be.x; x[q][1] = a.y + bq.y + be.y;
    x[q][2] = a.z + bq.z + be.z; x[q][3] = a.w + bq.w + be.w;
  }
  float s = 0;
#pragma unroll
  for (int q = 0; q < 4; ++q) s += x[q][0] + x[q][1] + x[q][2] + x[q][3];
#pragma unroll
  for (int off = 32; off; off >>= 1) s += __shfl_down(s, off);
  const float mu = __shfl(s, 0) * (1.0f / HID_);
  float sq = 0;
#pragma unroll
  for (int q = 0; q < 4; ++q)
#pragma unroll
    for (int i = 0; i < 4; ++i) {
      float d = x[q][i] - mu;
      sq += d * d;
    }
#pragma unroll
  for (int off = 32; off; off >>= 1) sq += __shfl_down(sq, off);
  const float inv = 1.0f / sqrtf(__shfl(sq, 0) * (1.0f / HID_) + EPS_);
  float c0 = 0, c1 = 0, c2 = 0;
#pragma unroll
  for (int q = 0; q < 4; ++q) {
    const int d = q * 256 + lane * 4;
    float4 gg = *(const float4*)&g1[(size_t)e * HID_ + d];
    float4 bb = *(const float4*)&beta1[(size_t)e * HID_ + d];
    float gv[4] = {gg.x, gg.y, gg.z, gg.w};
    float bv[4] = {bb.x, bb.y, bb.z, bb.w};
#pragma unroll
    for (int i = 0; i < 4; ++i) {
      float v = (x[q][i] - mu) * inv * gv[i] + bv[i];
      v = 0.5f * v * (1.0f + erff(v * 0.70710678118654752440f));  // exact gelu
      const float* wc = &Wcomb[(size_t)(e * HID_ + d + i) * 3];
      c0 = fmaf(v, wc[0], c0); c1 = fmaf(v, wc[1], c1); c2 = fmaf(v, wc[2], c2);
    }
  }
  waveRed3(c0, c1, c2);
  if (lane == 0) {
    sCtr[w][0] = prob * (c0 + bcomb[e * 3 + 0]);
    sCtr[w][1] = prob * (c1 + bcomb[e * 3 + 1]);
    sCtr[w][2] = prob * (c2 + bcomb[e * 3 + 2]);
  }

  {
    const int h0 = w * 256 + lane * 4;
    fvec4 ta = nt_load4f(&tA[(size_t)b * H_ + h0]);
    fvec4 tb = nt_load4f(&tB[(size_t)b * H_ + h0]);
    float4 bdv = *(const float4*)&bd[h0];
    float tvv[4] = {tanhf(ta.x + tb.x + bdv.x), tanhf(ta.y + tb.y + bdv.y),
                    tanhf(ta.z + tb.z + bdv.z), tanhf(ta.w + tb.w + bdv.w)};
    float o0 = 0, o1 = 0, o2 = 0;
#pragma unroll
    for (int i = 0; i < 4; ++i) {
      const float* wo = &Wo[(size_t)(h0 + i) * 3];
      o0 = fmaf(tvv[i], wo[0], o0); o1 = fmaf(tvv[i], wo[1], o1); o2 = fmaf(tvv[i], wo[2], o2);
    }
    waveRed3(o0, o1, o2);
    if (lane == 0) { sOl[w][0] = o0; sOl[w][1] = o1; sOl[w][2] = o2; }
  }
  __syncthreads();

  if (tid == 0) {
    float comb[6];
#pragma unroll
    for (int c = 0; c < 3; ++c) {
      comb[c] = sOl[0][c] + sOl[1][c] + sOl[2][c] + sOl[3][c] + bo[c];
      comb[3 + c] = sCtr[0][c] + sCtr[1][c] + sCtr[2][c] + sCtr[3][c];
    }
    float z[3];
#pragma unroll
    for (int c = 0; c < 3; ++c) {
      float sv = bf1[c];
#pragma unroll
      for (int i = 0; i < 6; ++i) sv = fmaf(comb[i], Wf1[i * 3 + c], sv);
      z[c] = sv;
    }
    float mu3 = (z[0] + z[1] + z[2]) * (1.0f / 3.0f);
    float v0 = z[0] - mu3, v1 = z[1] - mu3, v2 = z[2] - mu3;
    float var = (v0 * v0 + v1 * v1 + v2 * v2) * (1.0f / 3.0f);
    float inv3 = 1.0f / sqrtf(var + EPS_);
    float r[3];
#pragma unroll
    for (int c = 0; c < 3; ++c) {
      float zz = (z[c] - mu3) * inv3 * gf[c] + betaf[c];
      r[c] = zz > 0.0f ? zz : 0.0f;
    }
#pragma unroll
    for (int c = 0; c < 3; ++c) {
      float sv = bf2[c];
#pragma unroll
      for (int i = 0; i < 3; ++i) sv = fmaf(r[i], Wf2[i * 3 + c], sv);
      out[b * 3 + c] = sv;
    }
  }
}

// ---------------------------------------------------------------------------
extern "C" void kernel_launch(void* const* d_in, const int* in_sizes, int n_in,
                              void* d_out, int out_size, void* d_ws, size_t ws_size,
                              hipStream_t stream) {
  const float* hs    = (const float*)d_in[0];
  const float* Wd    = (const float*)d_in[1];
  const float* bd    = (const float*)d_in[2];
  const float* Wo    = (const float*)d_in[3];
  const float* bo    = (const float*)d_in[4];
  const float* Wr    = (const float*)d_in[5];
  const float* br    = (const float*)d_in[6];
  const float* We1   = (const float*)d_in[7];
  const float* be1   = (const float*)d_in[8];
  const float* g1    = (const float*)d_in[9];
  const float* beta1 = (const float*)d_in[10];
  const float* We2   = (const float*)d_in[11];
  const float* be2   = (const float*)d_in[12];
  const float* Wp    = (const float*)d_in[13];
  const float* bp    = (const float*)d_in[14];
  const float* Wf1   = (const float*)d_in[15];
  const float* bf1   = (const float*)d_in[16];
  const float* gf    = (const float*)d_in[17];
  const float* betaf = (const float*)d_in[18];
  const float* Wf2   = (const float*)d_in[19];
  const float* bf2   = (const float*)d_in[20];
  float* out = (float*)d_out;

  char* w = (char*)d_ws;
  size_t off = 0;
  auto alloc = [&](size_t bytes) {
    void* p = w + off;
    off = (off + bytes + 255) & ~(size_t)255;
    return p;
  };
  ushort* m_hi   = (ushort*)alloc((size_t)B_ * H_ * 2);
  ushort* m_lo   = (ushort*)alloc((size_t)B_ * H_ * 2);
  ushort* cls_hi = (ushort*)alloc((size_t)B_ * H_ * 2);
  ushort* cls_lo = (ushort*)alloc((size_t)B_ * H_ * 2);
  float* ws_tA   = (float*)alloc((size_t)B_ * H_ * 4);
  float* ws_tB   = (float*)alloc((size_t)B_ * H_ * 4);
  float* ws_h1A  = (float*)alloc((size_t)B_ * K_ * HID_ * 4);
  float* ws_h1B  = (float*)alloc((size_t)B_ * K_ * HID_ * 4);
  float* ws_wc   = (float*)alloc((size_t)E_ * HID_ * 3 * 4);
  float* ws_bc   = (float*)alloc(E_ * 3 * 4);
  float* ws_prob = (float*)alloc(B_ * K_ * 4);
  int* ws_idx = (int*)alloc(B_ * K_ * 4);
  int* ws_cnt = (int*)alloc(E_ * 4);
  int* ws_pl  = (int*)alloc(E_ * B_ * 4);
  if (off > ws_size) return;

  hipMemsetAsync(ws_cnt, 0, E_ * sizeof(int), stream);

  prep_kernel<<<NB_PREP, 256, 0, stream>>>(hs, We2, Wp, bp, Wr, br, be2,
                                           m_hi, m_lo, cls_hi, cls_lo,
                                           ws_wc, ws_bc,
                                           ws_idx, ws_prob, ws_cnt, ws_pl);
  gemm_mega<<<dim3(8, 16, 17), 512, 0, stream>>>(m_hi, m_lo, cls_hi, cls_lo,
                                                 Wd, We1, ws_cnt, ws_pl,
                                                 ws_tA, ws_tB, ws_h1A, ws_h1B);
  epi_kernel<<<B_, 256, 0, stream>>>(ws_tA, ws_tB, bd, Wo, bo, ws_h1A, ws_h1B, be1,
                                     g1, beta1, ws_idx, ws_prob, ws_wc, ws_bc,
                                     Wf1, bf1, gf, betaf, Wf2, bf2, out);
}

// Round 19
// 212.639 us; speedup vs baseline: 1.2080x; 1.0868x over previous
//
#include <hip/hip_runtime.h>
#include <math.h>

#define B_ 1024
#define S_ 128
#define H_ 1024
#define E_ 16
#define HID_ 1024
#define K_ 4
#define C_ 3
#define EPS_ 1e-5f

// prep kernel segment offsets (Wcomb moved into the GEMM launch z==17)
#define NB_MEAN 1024
#define NB_RT 256
#define NB_BC 4
#define OFF_RT (NB_MEAN)
#define OFF_BC (OFF_RT + NB_RT)
#define NB_PREP (OFF_BC + NB_BC)

typedef __attribute__((ext_vector_type(8))) __bf16 bf16x8;
typedef __attribute__((ext_vector_type(4))) float f32x4;
typedef __attribute__((ext_vector_type(4))) float fvec4;
typedef __attribute__((ext_vector_type(4))) unsigned short usvec4;
typedef __attribute__((ext_vector_type(8))) unsigned short usvec8;

__device__ __forceinline__ ushort bf16_rn(float f) {
  unsigned u = __float_as_uint(f);
  u += 0x7FFF + ((u >> 16) & 1);
  return (ushort)(u >> 16);
}
__device__ __forceinline__ float bf16_to_f(ushort h) {
  return __uint_as_float(((unsigned)h) << 16);
}
__device__ __forceinline__ void split2(float f, ushort& h, ushort& l) {
  h = bf16_rn(f);
  l = bf16_rn(f - bf16_to_f(h));
}
__device__ __forceinline__ void gload_lds16(const void* g, void* l) {
  __builtin_amdgcn_global_load_lds((const __attribute__((address_space(1))) void*)g,
                                   (__attribute__((address_space(3))) void*)l, 16, 0, 0);
}
// Explicit LDS-DMA drain (rule #18: asm waitcnt + sched_barrier(0)).
#define DMA_DRAIN() do {                                  \
    asm volatile("s_waitcnt vmcnt(0)" ::: "memory");      \
    __builtin_amdgcn_sched_barrier(0);                    \
  } while (0)

// nontemporal shims — ONLY for true stream-once data.
__device__ __forceinline__ fvec4 nt_load4f(const float* p) {
  return __builtin_nontemporal_load((const fvec4*)p);
}
__device__ __forceinline__ void st4us(ushort* p, ushort a, ushort b, ushort c, ushort d) {
  usvec4 v; v.x = a; v.y = b; v.z = c; v.w = d;
  *(usvec4*)p = v;
}
__device__ __forceinline__ void nt_store1f(float* p, float v) {
  __builtin_nontemporal_store(v, p);
}
__device__ __forceinline__ void waveRed3(float& s0, float& s1, float& s2) {
#pragma unroll
  for (int off = 32; off; off >>= 1) {
    s0 += __shfl_down(s0, off); s1 += __shfl_down(s1, off); s2 += __shfl_down(s2, off);
  }
}

// ---------------------------------------------------------------------------
// Phase A: prep — mean/cls splits, router, bcomb. (Wcomb moved to GEMM z=17:
// both its source (We2) and sink (epi) permit it, and the 64 MB read then
// overlaps GEMM compute instead of extending the BW-bound prep phase.)
// ---------------------------------------------------------------------------
__global__ __launch_bounds__(256) void prep_kernel(
    const float* __restrict__ hs,
    const float* __restrict__ Wp, const float* __restrict__ bp,
    const float* __restrict__ Wr, const float* __restrict__ br,
    const float* __restrict__ be2,
    ushort* __restrict__ m_hi, ushort* __restrict__ m_lo,
    ushort* __restrict__ cls_hi, ushort* __restrict__ cls_lo,
    float* __restrict__ bcomb,
    int* __restrict__ topk_idx, float* __restrict__ topk_prob,
    int* __restrict__ counts, int* __restrict__ pairlist) {
  const int blk = blockIdx.x;
  const int tid = threadIdx.x;

  if (blk < NB_MEAN) {
    int gid = blk * 256 + tid;
    int b = gid >> 8;
    int h4 = (gid & 255) << 2;
    const float* p = hs + (size_t)b * S_ * H_ + h4;
    fvec4 v0 = nt_load4f(p);
    float sx = v0.x, sy = v0.y, sz = v0.z, sw = v0.w;
#pragma unroll 8
    for (int s = 1; s < S_; ++s) {
      fvec4 v = nt_load4f(p + (size_t)s * H_);
      sx += v.x; sy += v.y; sz += v.z; sw += v.w;
    }
    const float inv = 1.0f / (float)S_;
    float mv[4] = {sx * inv, sy * inv, sz * inv, sw * inv};
    float cv[4] = {v0.x, v0.y, v0.z, v0.w};
    ushort mh[4], ml[4], ch[4], cl[4];
#pragma unroll
    for (int i = 0; i < 4; ++i) { split2(mv[i], mh[i], ml[i]); split2(cv[i], ch[i], cl[i]); }
    size_t o = (size_t)b * H_ + h4;
    st4us(&m_hi[o], mh[0], mh[1], mh[2], mh[3]);
    st4us(&m_lo[o], ml[0], ml[1], ml[2], ml[3]);
    st4us(&cls_hi[o], ch[0], ch[1], ch[2], ch[3]);
    st4us(&cls_lo[o], cl[0], cl[1], cl[2], cl[3]);
  } else if (blk < OFF_BC) {
    const int lane = tid & 63;
    const int b = (blk - OFF_RT) * 4 + (tid >> 6);
    const float* cls = hs + (size_t)b * S_ * H_;
    const int e = lane & 15, part = lane >> 4;
    float sum = 0.0f;
    for (int i = part * 256; i < part * 256 + 256; ++i)
      sum = fmaf(cls[i], Wr[i * E_ + e], sum);
    sum += __shfl_down(sum, 32);
    sum += __shfl_down(sum, 16);
    float lg[E_];
#pragma unroll
    for (int i = 0; i < E_; ++i) lg[i] = __shfl(sum, i);
    if (lane == 0) {
      for (int i = 0; i < E_; ++i) lg[i] += br[i];
      int idx[K_]; float tv[K_];
      for (int k = 0; k < K_; ++k) {
        int bi = 0; float bv = -1e30f;
        for (int i = 0; i < E_; ++i) { if (lg[i] > bv) { bv = lg[i]; bi = i; } }
        idx[k] = bi; tv[k] = bv; lg[bi] = -1e30f;
      }
      float mx = tv[0], ssum = 0.0f, p[K_];
      for (int k = 0; k < K_; ++k) { p[k] = expf(tv[k] - mx); ssum += p[k]; }
      for (int k = 0; k < K_; ++k) {
        p[k] /= ssum;
        topk_idx[b * K_ + k] = idx[k];
        topk_prob[b * K_ + k] = p[k];
        int pos = atomicAdd(&counts[idx[k]], 1);
        pairlist[idx[k] * B_ + pos] = b * K_ + k;
      }
    }
  } else {
    const int e = (blk - OFF_BC) * 4 + (tid >> 6);
    const int lane = tid & 63;
    const float* wrp = be2 + (size_t)e * HID_;
    float s0 = 0, s1 = 0, s2 = 0;
    for (int f = lane; f < HID_; f += 64) {
      float v = wrp[f];
      s0 = fmaf(v, Wp[f * 3 + 0], s0);
      s1 = fmaf(v, Wp[f * 3 + 1], s1);
      s2 = fmaf(v, Wp[f * 3 + 2], s2);
    }
    waveRed3(s0, s1, s2);
    if (lane == 0) {
      bcomb[e * 3 + 0] = s0 + bp[0]; bcomb[e * 3 + 1] = s1 + bp[1]; bcomb[e * 3 + 2] = s2 + bp[2];
    }
  }
}

// ---------------------------------------------------------------------------
// Phase B: unified MFMA GEMM (best-measured config) + z==17 Wcomb segment.
// z<16: expert GEMM; z==16: cls@Wd; z==17: Wcomb = We2 @ Wp (128 blocks,
// 16 rows/wave — BW-bound reads that overlap the GEMM's compute; consumed
// only by the epi launch, so no intra-grid ordering hazard).
// ---------------------------------------------------------------------------
__global__ __launch_bounds__(512) void gemm_mega(
    const ushort* __restrict__ m_hi, const ushort* __restrict__ m_lo,
    const ushort* __restrict__ cls_hi, const ushort* __restrict__ cls_lo,
    const float* __restrict__ Wd, const float* __restrict__ We1,
    const float* __restrict__ We2, const float* __restrict__ Wp,
    const int* __restrict__ counts, const int* __restrict__ pairlist,
    float* __restrict__ tA, float* __restrict__ tB,
    float* __restrict__ h1A, float* __restrict__ h1B,
    float* __restrict__ Wcomb) {
  __shared__ __align__(16) ushort ldsAh0[4096], ldsAl0[4096], ldsBh0[4096], ldsBl0[4096];
  __shared__ __align__(16) ushort ldsAh1[4096], ldsAl1[4096], ldsBh1[4096], ldsBl1[4096];
  const int z = blockIdx.z;
  const int tid = threadIdx.x;
  const int lane = tid & 63, w = tid >> 6;          // w in 0..7

  if (z == 17) {
    // ---- Wcomb[row,:] = We2[row,:] @ Wp (16 rows per wave) ----
    const int blk_id = blockIdx.y * 8 + blockIdx.x;     // [0,128)
    const int row0 = blk_id * 128 + w * 16;
    for (int rr = 0; rr < 16; ++rr) {
      const int row = row0 + rr;
      const float* wrp = We2 + (size_t)row * HID_;
      float s0 = 0, s1 = 0, s2 = 0;
#pragma unroll
      for (int it = 0; it < 4; ++it) {
        const int f0 = it * 256 + lane * 4;
        fvec4 v = nt_load4f(&wrp[f0]);
        s0 = fmaf(v.x, Wp[(f0 + 0) * 3 + 0], s0);
        s1 = fmaf(v.x, Wp[(f0 + 0) * 3 + 1], s1);
        s2 = fmaf(v.x, Wp[(f0 + 0) * 3 + 2], s2);
        s0 = fmaf(v.y, Wp[(f0 + 1) * 3 + 0], s0);
        s1 = fmaf(v.y, Wp[(f0 + 1) * 3 + 1], s1);
        s2 = fmaf(v.y, Wp[(f0 + 1) * 3 + 2], s2);
        s0 = fmaf(v.z, Wp[(f0 + 2) * 3 + 0], s0);
        s1 = fmaf(v.z, Wp[(f0 + 2) * 3 + 1], s1);
        s2 = fmaf(v.z, Wp[(f0 + 2) * 3 + 2], s2);
        s0 = fmaf(v.w, Wp[(f0 + 3) * 3 + 0], s0);
        s1 = fmaf(v.w, Wp[(f0 + 3) * 3 + 1], s1);
        s2 = fmaf(v.w, Wp[(f0 + 3) * 3 + 2], s2);
      }
      waveRed3(s0, s1, s2);
      if (lane == 0) {
        Wcomb[row * 3 + 0] = s0; Wcomb[row * 3 + 1] = s1; Wcomb[row * 3 + 2] = s2;
      }
    }
    return;
  }

  const int mt = blockIdx.y >> 1, kh = blockIdx.y & 1;
  const int m0 = mt * 128, n0 = blockIdx.x * 128;
  const int kbase = kh * 512;
  int n_e;
  if (z == 16) n_e = B_;
  else { n_e = counts[z]; if (m0 >= n_e) return; }

  // ---- staging-role setup ----
  const ushort* srcp[4];        // A waves (w<4): 4 subtiles via gload_lds
  ushort* dstA0 = nullptr; ushort* dstA1 = nullptr;
  const float* bbase[2];        // B waves (w>=4): 2 subtiles, fp32 strided
  int bsub[2];
  const int halfq = w & 1;
  if (w < 4) {
    const int warr = w >> 1;    // 0 = A_hi, 1 = A_lo
    dstA0 = (warr == 0) ? ldsAh0 : ldsAl0;
    dstA1 = (warr == 0) ? ldsAh1 : ldsAl1;
    const ushort* sbase;
    if (z == 16) sbase = (warr == 0) ? cls_hi : cls_lo;
    else         sbase = (warr == 0) ? m_hi  : m_lo;
#pragma unroll
    for (int sl = 0; sl < 4; ++sl) {
      int s = halfq * 4 + sl;
      int r = m0 + s * 16 + (lane & 15);
      if (z != 16) {
        if (r >= n_e) r = n_e - 1;
        r = pairlist[z * B_ + r] >> 2;      // sample index
      }
      srcp[sl] = sbase + (size_t)r * H_ + ((lane >> 4) << 3);
    }
  } else {
    const float* Wfp = (z == 16) ? Wd : (We1 + (size_t)z * H_ * HID_);
#pragma unroll
    for (int sl = 0; sl < 2; ++sl) {
      int s = (w - 4) * 2 + sl;
      bsub[sl] = s;
      int col = n0 + s * 16 + (lane & 15);
      bbase[sl] = Wfp + col + (size_t)(lane >> 4) * 8 * HID_;
    }
  }

  const int wr = w >> 2, wc = w & 3;                 // compute role: 2x4 grid
  f32x4 acc[4][2] = {};

  auto stageA = [&](int kofs, ushort* dst) {
#pragma unroll
    for (int sl = 0; sl < 4; ++sl)
      gload_lds16(srcp[sl] + kofs, dst + (halfq * 4 + sl) * 512);
  };
  auto stageB = [&](int kofs, ushort* dBh, ushort* dBl) {
#pragma unroll
    for (int sl = 0; sl < 2; ++sl) {
      const float* bp = bbase[sl] + (size_t)kofs * HID_;
      float f[8];
#pragma unroll
      for (int j = 0; j < 8; ++j) f[j] = bp[(size_t)j * HID_];
      usvec8 vh, vl;
#pragma unroll
      for (int j = 0; j < 8; ++j) {
        ushort hi, lo;
        split2(f[j], hi, lo);
        vh[j] = hi; vl[j] = lo;
      }
      const int off = bsub[sl] * 512 + lane * 8;
      *(usvec8*)&dBh[off] = vh;
      *(usvec8*)&dBl[off] = vl;
    }
  };
  auto stage_buf0 = [&](int kofs) {
    if (w < 4) stageA(kofs, dstA0);
    else stageB(kofs, ldsBh0, ldsBl0);
  };
  auto stage_buf1 = [&](int kofs) {
    if (w < 4) stageA(kofs, dstA1);
    else stageB(kofs, ldsBh1, ldsBl1);
  };
  auto compute = [&](const ushort* Ah, const ushort* Al,
                     const ushort* Bh, const ushort* Bl) {
    bf16x8 ah[4], al[4], bh[2], bl[2];
#pragma unroll
    for (int i = 0; i < 4; ++i) {
      int off = (wr * 4 + i) * 512 + lane * 8;
      ah[i] = *(const bf16x8*)&Ah[off];
      al[i] = *(const bf16x8*)&Al[off];
    }
#pragma unroll
    for (int j = 0; j < 2; ++j) {
      int off = (wc * 2 + j) * 512 + lane * 8;
      bh[j] = *(const bf16x8*)&Bh[off];
      bl[j] = *(const bf16x8*)&Bl[off];
    }
#pragma unroll
    for (int i = 0; i < 4; ++i)
#pragma unroll
      for (int j = 0; j < 2; ++j) {
        acc[i][j] = __builtin_amdgcn_mfma_f32_16x16x32_bf16(ah[i], bh[j], acc[i][j], 0, 0, 0);
        acc[i][j] = __builtin_amdgcn_mfma_f32_16x16x32_bf16(ah[i], bl[j], acc[i][j], 0, 0, 0);
        acc[i][j] = __builtin_amdgcn_mfma_f32_16x16x32_bf16(al[i], bh[j], acc[i][j], 0, 0, 0);
      }
  };

  stage_buf0(kbase);
  DMA_DRAIN();
  __syncthreads();

#pragma unroll 1
  for (int tt = 0; tt < 8; ++tt) {
    const int t0 = tt * 2;
    stage_buf1(kbase + (t0 + 1) * 32);
    compute(ldsAh0, ldsAl0, ldsBh0, ldsBl0);
    DMA_DRAIN();
    __syncthreads();
    if (tt < 7) stage_buf0(kbase + (t0 + 2) * 32);
    compute(ldsAh1, ldsAl1, ldsBh1, ldsBl1);
    DMA_DRAIN();
    __syncthreads();
  }

  const int lr = (lane >> 4) << 2, lc = lane & 15;
  if (z == 16) {
    float* tp = kh ? tB : tA;
#pragma unroll
    for (int i = 0; i < 4; ++i) {
      int row = m0 + wr * 64 + i * 16 + lr;
#pragma unroll
      for (int j = 0; j < 2; ++j) {
        int col = n0 + wc * 32 + j * 16 + lc;
#pragma unroll
        for (int r = 0; r < 4; ++r)
          nt_store1f(&tp[(size_t)(row + r) * H_ + col], acc[i][j][r]);
      }
    }
  } else {
    float* hp = kh ? h1B : h1A;
#pragma unroll
    for (int i = 0; i < 4; ++i) {
      int pr[4]; bool ok[4];
#pragma unroll
      for (int r = 0; r < 4; ++r) {
        int li = m0 + wr * 64 + i * 16 + lr + r;
        ok[r] = li < n_e;
        pr[r] = pairlist[z * B_ + (ok[r] ? li : n_e - 1)];
      }
#pragma unroll
      for (int j = 0; j < 2; ++j) {
        int col = n0 + wc * 32 + j * 16 + lc;
#pragma unroll
        for (int r = 0; r < 4; ++r)
          if (ok[r]) nt_store1f(&hp[(size_t)pr[r] * HID_ + col], acc[i][j][r]);
      }
    }
  }
}

// ---------------------------------------------------------------------------
// Phase C: fused epilogue (unchanged). One block per sample b.
// ---------------------------------------------------------------------------
__global__ __launch_bounds__(256) void epi_kernel(
    const float* __restrict__ tA, const float* __restrict__ tB,
    const float* __restrict__ bd,
    const float* __restrict__ Wo, const float* __restrict__ bo,
    const float* __restrict__ h1A, const float* __restrict__ h1B,
    const float* __restrict__ be1,
    const float* __restrict__ g1, const float* __restrict__ beta1,
    const int* __restrict__ topk_idx, const float* __restrict__ topk_prob,
    const float* __restrict__ Wcomb, const float* __restrict__ bcomb,
    const float* __restrict__ Wf1, const float* __restrict__ bf1,
    const float* __restrict__ gf, const float* __restrict__ betaf,
    const float* __restrict__ Wf2, const float* __restrict__ bf2,
    float* __restrict__ out) {
  const int b = blockIdx.x;
  const int tid = threadIdx.x;
  const int w = tid >> 6, lane = tid & 63;
  __shared__ float sCtr[4][3];
  __shared__ float sOl[4][3];

  const int pair = b * K_ + w;
  const int e = topk_idx[pair];
  const float prob = topk_prob[pair];
  const float* hrA = h1A + (size_t)pair * HID_;
  const float* hrB = h1B + (size_t)pair * HID_;
  const float* ber = be1 + (size_t)e * HID_;
  float x[4][4];
#pragma unroll
  for (int q = 0; q < 4; ++q) {
    const int d = q * 256 + lane * 4;
    fvec4 a = nt_load4f(&hrA[d]);
    fvec4 bq = nt_load4f(&hrB[d]);
    float4 be = *(const float4*)&ber[d];
    x[q][0] = a.x + bq.x + be.x; x[q][1] = a.y + bq.y + be.y;
    x[q][2] = a.z + bq.z + be.z; x[q][3] = a.w + bq.w + be.w;
  }
  float s = 0;
#pragma unroll
  for (int q = 0; q < 4; ++q) s += x[q][0] + x[q][1] + x[q][2] + x[q][3];
#pragma unroll
  for (int off = 32; off; off >>= 1) s += __shfl_down(s, off);
  const float mu = __shfl(s, 0) * (1.0f / HID_);
  float sq = 0;
#pragma unroll
  for (int q = 0; q < 4; ++q)
#pragma unroll
    for (int i = 0; i < 4; ++i) {
      float d = x[q][i] - mu;
      sq += d * d;
    }
#pragma unroll
  for (int off = 32; off; off >>= 1) sq += __shfl_down(sq, off);
  const float inv = 1.0f / sqrtf(__shfl(sq, 0) * (1.0f / HID_) + EPS_);
  float c0 = 0, c1 = 0, c2 = 0;
#pragma unroll
  for (int q = 0; q < 4; ++q) {
    const int d = q * 256 + lane * 4;
    float4 gg = *(const float4*)&g1[(size_t)e * HID_ + d];
    float4 bb = *(const float4*)&beta1[(size_t)e * HID_ + d];
    float gv[4] = {gg.x, gg.y, gg.z, gg.w};
    float bv[4] = {bb.x, bb.y, bb.z, bb.w};
#pragma unroll
    for (int i = 0; i < 4; ++i) {
      float v = (x[q][i] - mu) * inv * gv[i] + bv[i];
      v = 0.5f * v * (1.0f + erff(v * 0.70710678118654752440f));  // exact gelu
      const float* wc = &Wcomb[(size_t)(e * HID_ + d + i) * 3];
      c0 = fmaf(v, wc[0], c0); c1 = fmaf(v, wc[1], c1); c2 = fmaf(v, wc[2], c2);
    }
  }
  waveRed3(c0, c1, c2);
  if (lane == 0) {
    sCtr[w][0] = prob * (c0 + bcomb[e * 3 + 0]);
    sCtr[w][1] = prob * (c1 + bcomb[e * 3 + 1]);
    sCtr[w][2] = prob * (c2 + bcomb[e * 3 + 2]);
  }

  {
    const int h0 = w * 256 + lane * 4;
    fvec4 ta = nt_load4f(&tA[(size_t)b * H_ + h0]);
    fvec4 tb = nt_load4f(&tB[(size_t)b * H_ + h0]);
    float4 bdv = *(const float4*)&bd[h0];
    float tvv[4] = {tanhf(ta.x + tb.x + bdv.x), tanhf(ta.y + tb.y + bdv.y),
                    tanhf(ta.z + tb.z + bdv.z), tanhf(ta.w + tb.w + bdv.w)};
    float o0 = 0, o1 = 0, o2 = 0;
#pragma unroll
    for (int i = 0; i < 4; ++i) {
      const float* wo = &Wo[(size_t)(h0 + i) * 3];
      o0 = fmaf(tvv[i], wo[0], o0); o1 = fmaf(tvv[i], wo[1], o1); o2 = fmaf(tvv[i], wo[2], o2);
    }
    waveRed3(o0, o1, o2);
    if (lane == 0) { sOl[w][0] = o0; sOl[w][1] = o1; sOl[w][2] = o2; }
  }
  __syncthreads();

  if (tid == 0) {
    float comb[6];
#pragma unroll
    for (int c = 0; c < 3; ++c) {
      comb[c] = sOl[0][c] + sOl[1][c] + sOl[2][c] + sOl[3][c] + bo[c];
      comb[3 + c] = sCtr[0][c] + sCtr[1][c] + sCtr[2][c] + sCtr[3][c];
    }
    float z[3];
#pragma unroll
    for (int c = 0; c < 3; ++c) {
      float sv = bf1[c];
#pragma unroll
      for (int i = 0; i < 6; ++i) sv = fmaf(comb[i], Wf1[i * 3 + c], sv);
      z[c] = sv;
    }
    float mu3 = (z[0] + z[1] + z[2]) * (1.0f / 3.0f);
    float v0 = z[0] - mu3, v1 = z[1] - mu3, v2 = z[2] - mu3;
    float var = (v0 * v0 + v1 * v1 + v2 * v2) * (1.0f / 3.0f);
    float inv3 = 1.0f / sqrtf(var + EPS_);
    float r[3];
#pragma unroll
    for (int c = 0; c < 3; ++c) {
      float zz = (z[c] - mu3) * inv3 * gf[c] + betaf[c];
      r[c] = zz > 0.0f ? zz : 0.0f;
    }
#pragma unroll
    for (int c = 0; c < 3; ++c) {
      float sv = bf2[c];
#pragma unroll
      for (int i = 0; i < 3; ++i) sv = fmaf(r[i], Wf2[i * 3 + c], sv);
      out[b * 3 + c] = sv;
    }
  }
}

// ---------------------------------------------------------------------------
extern "C" void kernel_launch(void* const* d_in, const int* in_sizes, int n_in,
                              void* d_out, int out_size, void* d_ws, size_t ws_size,
                              hipStream_t stream) {
  const float* hs    = (const float*)d_in[0];
  const float* Wd    = (const float*)d_in[1];
  const float* bd    = (const float*)d_in[2];
  const float* Wo    = (const float*)d_in[3];
  const float* bo    = (const float*)d_in[4];
  const float* Wr    = (const float*)d_in[5];
  const float* br    = (const float*)d_in[6];
  const float* We1   = (const float*)d_in[7];
  const float* be1   = (const float*)d_in[8];
  const float* g1    = (const float*)d_in[9];
  const float* beta1 = (const float*)d_in[10];
  const float* We2   = (const float*)d_in[11];
  const float* be2   = (const float*)d_in[12];
  const float* Wp    = (const float*)d_in[13];
  const float* bp    = (const float*)d_in[14];
  const float* Wf1   = (const float*)d_in[15];
  const float* bf1   = (const float*)d_in[16];
  const float* gf    = (const float*)d_in[17];
  const float* betaf = (const float*)d_in[18];
  const float* Wf2   = (const float*)d_in[19];
  const float* bf2   = (const float*)d_in[20];
  float* out = (float*)d_out;

  char* w = (char*)d_ws;
  size_t off = 0;
  auto alloc = [&](size_t bytes) {
    void* p = w + off;
    off = (off + bytes + 255) & ~(size_t)255;
    return p;
  };
  ushort* m_hi   = (ushort*)alloc((size_t)B_ * H_ * 2);
  ushort* m_lo   = (ushort*)alloc((size_t)B_ * H_ * 2);
  ushort* cls_hi = (ushort*)alloc((size_t)B_ * H_ * 2);
  ushort* cls_lo = (ushort*)alloc((size_t)B_ * H_ * 2);
  float* ws_tA   = (float*)alloc((size_t)B_ * H_ * 4);
  float* ws_tB   = (float*)alloc((size_t)B_ * H_ * 4);
  float* ws_h1A  = (float*)alloc((size_t)B_ * K_ * HID_ * 4);
  float* ws_h1B  = (float*)alloc((size_t)B_ * K_ * HID_ * 4);
  float* ws_wc   = (float*)alloc((size_t)E_ * HID_ * 3 * 4);
  float* ws_bc   = (float*)alloc(E_ * 3 * 4);
  float* ws_prob = (float*)alloc(B_ * K_ * 4);
  int* ws_idx = (int*)alloc(B_ * K_ * 4);
  int* ws_cnt = (int*)alloc(E_ * 4);
  int* ws_pl  = (int*)alloc(E_ * B_ * 4);
  if (off > ws_size) return;

  hipMemsetAsync(ws_cnt, 0, E_ * sizeof(int), stream);

  prep_kernel<<<NB_PREP, 256, 0, stream>>>(hs, Wp, bp, Wr, br, be2,
                                           m_hi, m_lo, cls_hi, cls_lo,
                                           ws_bc, ws_idx, ws_prob, ws_cnt, ws_pl);
  gemm_mega<<<dim3(8, 16, 18), 512, 0, stream>>>(m_hi, m_lo, cls_hi, cls_lo,
                                                 Wd, We1, We2, Wp, ws_cnt, ws_pl,
                                                 ws_tA, ws_tB, ws_h1A, ws_h1B, ws_wc);
  epi_kernel<<<B_, 256, 0, stream>>>(ws_tA, ws_tB, bd, Wo, bo, ws_h1A, ws_h1B, be1,
                                     g1, beta1, ws_idx, ws_prob, ws_wc, ws_bc,
                                     Wf1, bf1, gf, betaf, Wf2, bf2, out);
}